// Round 14
// baseline (137.099 us; speedup 1.0000x reference)
//
#include <hip/hip_runtime.h>
#include <hip/hip_bf16.h>
#include <hip/hip_cooperative_groups.h>

#define NB 64
#define NL 512
#define ND 128
#define NK 256   // concat(Q,UQ) contraction dim

typedef unsigned short ush;
typedef __attribute__((ext_vector_type(8))) short short8;
typedef __attribute__((ext_vector_type(16))) float f32x16;

// Fragment layouts (bf16), one 32x32x16-MFMA operand chunk per lane:
//  QU_f/KU_f: elem off = ((p*16 + ks)*64 + lane)*8 ; holds row p*32+(lane&31),
//             k = ks*16+(lane>>5)*8 .. +7.  p GLOBAL row-panel (batch*16 + local).
//  Vb_f:      elem off = ((p*32 + ks)*64 + lane)*8 ; holds Vv row p*32+(lane&31),
//             l = ks*16+(lane>>5)*8 .. +7.  p GLOBAL (= rt).

__device__ __forceinline__ ush f2bs(float f) {
    union { __hip_bfloat16 h; ush u; } cv;
    cv.h = __float2bfloat16(f);
    return cv.u;
}
__device__ __forceinline__ short8 pack_bf8(float4 a, float4 b) {
    short8 r;
    r[0] = (short)f2bs(a.x); r[1] = (short)f2bs(a.y);
    r[2] = (short)f2bs(a.z); r[3] = (short)f2bs(a.w);
    r[4] = (short)f2bs(b.x); r[5] = (short)f2bs(b.y);
    r[6] = (short)f2bs(b.z); r[7] = (short)f2bs(b.w);
    return r;
}
__device__ __forceinline__ f32x16 zero16() {
    f32x16 z = {0.f,0.f,0.f,0.f,0.f,0.f,0.f,0.f,0.f,0.f,0.f,0.f,0.f,0.f,0.f,0.f};
    return z;
}

// ---------------- Kernel W: convert 5 weight matrices to bf16 ----------------
__global__ __launch_bounds__(256) void wconv_kernel(
    const float* __restrict__ W0, const float* __restrict__ W1,
    const float* __restrict__ W2, const float* __restrict__ W3,
    const float* __restrict__ W4, ush* __restrict__ Wb)
{
    const int m = blockIdx.y;
    const float* W = (m == 0) ? W0 : (m == 1) ? W1 : (m == 2) ? W2 : (m == 3) ? W3 : W4;
    const int e = (blockIdx.x * 256 + threadIdx.x) * 4;
    float4 v = *(const float4*)(W + e);
    ushort4 o;
    o.x = f2bs(v.x); o.y = f2bs(v.y); o.z = f2bs(v.z); o.w = f2bs(v.w);
    *(ushort4*)(Wb + m * 16384 + e) = o;
}

// ---------------- Kernel PQK: Q/K/UQ/UK projections -> fragment outputs ----------------
// 1D grid 1024 = 8 XCD x 128; rt = xcd*32 + (loc>>2), m = loc&3.
__global__ __launch_bounds__(256) void projqk_kernel(
    const float* __restrict__ EW, const float* __restrict__ ES,
    const ush* __restrict__ Wb,
    const float* __restrict__ b0, const float* __restrict__ b1,
    const float* __restrict__ b2, const float* __restrict__ b3,
    ush* __restrict__ QUf, ush* __restrict__ KUf)
{
    __shared__ ush Tls[4][2048];
    const int f = blockIdx.x;
    const int xcd = f & 7, loc = f >> 3;
    const int rt = xcd * 32 + (loc >> 2);
    const int m  = loc & 3;
    const int tid = threadIdx.x, w = tid >> 6, lane = tid & 63;
    const int l5 = lane & 31, hi = lane >> 5;
    const float* X = (m >= 2) ? ES : EW;
    const int rbase = rt * 128 + w * 32;

    const float* xr = X + (size_t)(rbase + l5) * ND + hi * 8;
    short8 af[8];
    #pragma unroll
    for (int ks = 0; ks < 8; ++ks)
        af[ks] = pack_bf8(*(const float4*)(xr + ks * 16),
                          *(const float4*)(xr + ks * 16 + 4));

    const ush* Wm = Wb + m * 16384;
    const float* Bp = (m == 0) ? b0 : (m == 1) ? b1 : (m == 2) ? b2 : b3;
    const float scl = 0.044194173824159216f;  // 1/(2*sqrt(128))

    char* Tc = (char*)Tls[w];
    ush* dstf = (m == 0 || m == 2) ? QUf : KUf;
    const int ko = (m >= 2) ? 8 : 0;
    const int p_g = rt * 4 + w;

    #pragma unroll
    for (int pass = 0; pass < 2; ++pass) {
        f32x16 acc[2];
        acc[0] = zero16(); acc[1] = zero16();
        #pragma unroll
        for (int ks = 0; ks < 8; ++ks) {
            #pragma unroll
            for (int nbl = 0; nbl < 2; ++nbl) {
                const int nb = pass * 2 + nbl;
                short8 bf_ = *(const short8*)(Wm + (nb * 32 + l5) * 128 + ks * 16 + hi * 8);
                acc[nbl] = __builtin_amdgcn_mfma_f32_32x32x16_bf16(af[ks], bf_, acc[nbl], 0, 0, 0);
            }
        }
        #pragma unroll
        for (int nbl = 0; nbl < 2; ++nbl) {
            const int nb = pass * 2 + nbl;
            float bias = Bp[nb * 32 + l5];
            #pragma unroll
            for (int r6 = 0; r6 < 16; ++r6) {
                int row = (r6 & 3) + 8 * (r6 >> 2) + 4 * hi;
                int boff = row * 128 + (((nbl * 32 + l5) * 2) ^ ((row & 7) << 4));
                *(ush*)(Tc + boff) = f2bs((acc[nbl][r6] + bias) * scl);
            }
        }
        #pragma unroll
        for (int ks8 = 0; ks8 < 4; ++ks8) {
            int boff = l5 * 128 + ((ks8 * 32 + hi * 16) ^ ((l5 & 7) << 4));
            short8 v = *(const short8*)(Tc + boff);
            int ksg = ko + pass * 4 + ks8;
            *(short8*)(dstf + ((size_t)(p_g * 16 + ksg) * 64 + lane) * 8) = v;
        }
    }
}

// ---------------- Kernel PV: V projection -> Vv fragment output ----------------
__global__ __launch_bounds__(256) void projv_kernel(
    const float* __restrict__ EW, const ush* __restrict__ Wb,
    const float* __restrict__ b4, ush* __restrict__ Vbf)
{
    __shared__ ush lds[16384];
    const int f = blockIdx.x;
    const int rt = (f & 7) * 32 + (f >> 3);
    const int tid = threadIdx.x, w = tid >> 6, lane = tid & 63;
    const int l5 = lane & 31, hi = lane >> 5;
    const int rbase = rt * 128 + w * 32;

    const float* xr = EW + (size_t)(rbase + l5) * ND + hi * 8;
    short8 af[8];
    #pragma unroll
    for (int ks = 0; ks < 8; ++ks)
        af[ks] = pack_bf8(*(const float4*)(xr + ks * 16),
                          *(const float4*)(xr + ks * 16 + 4));

    const ush* Wm = Wb + 4 * 16384;
    f32x16 acc[4];
    acc[0] = zero16(); acc[1] = zero16(); acc[2] = zero16(); acc[3] = zero16();
    #pragma unroll
    for (int ks = 0; ks < 8; ++ks) {
        #pragma unroll
        for (int nb = 0; nb < 4; ++nb) {
            short8 bf_ = *(const short8*)(Wm + (nb * 32 + l5) * 128 + ks * 16 + hi * 8);
            acc[nb] = __builtin_amdgcn_mfma_f32_32x32x16_bf16(af[ks], bf_, acc[nb], 0, 0, 0);
        }
    }

    char* Lc = (char*)lds;
    #pragma unroll
    for (int nb = 0; nb < 4; ++nb) {
        float bias = b4[nb * 32 + l5];
        #pragma unroll
        for (int r6 = 0; r6 < 16; ++r6) {
            int row5 = (r6 & 3) + 8 * (r6 >> 2) + 4 * hi;
            int dl = w * 8 + (row5 >> 2);
            int lcol = (row5 & 3) * 128 + nb * 32 + l5;
            int boff = dl * 1024 + ((lcol * 2) ^ ((dl & 7) << 4));
            *(ush*)(Lc + boff) = f2bs(acc[nb][r6] + bias);
        }
    }
    __syncthreads();
    #pragma unroll
    for (int it = 0; it < 8; ++it) {
        int chunk = it * 256 + tid;
        int ks = chunk >> 6, ln = chunk & 63;
        int l5b = ln & 31, hib = ln >> 5;
        int boff = l5b * 1024 + ((ks * 32 + hib * 16) ^ ((l5b & 7) << 4));
        short8 v = *(const short8*)(Lc + boff);
        *(short8*)(Vbf + ((size_t)(rt * 32 + ks) * 64 + ln) * 8) = v;
    }
}

// ---------------- Cooperative fused kernel: alpha -> N(LDS) -> denom(atomic) -> PV ----------------
// grid 1024 (co-resident: 4 blocks/CU via LDS ~35KB, VGPR<=128).
// b = (f&7)*8 + ((f>>3)>>4), ct = (f>>3)&15 (32 out cols). Phase A: alpha for all 512 l
// x this block's 32 c; exp -> Pt LDS (bf16, pitch 1088B => 2-way conflicts only);
// per-row partial sums atomicAdd into dAcc[b][l]. grid.sync(). Phase B: PV / dAcc.
#define PT_PITCH 1088
__global__ __launch_bounds__(256, 4) void coop_kernel(
    const ush* __restrict__ QUf, const ush* __restrict__ KUf,
    const ush* __restrict__ Vbf, float* __restrict__ dAcc,
    float* __restrict__ out)
{
    __shared__ char Pt[32 * PT_PITCH];   // [c 0..31][l 0..511] bf16
    const int f = blockIdx.x;
    const int xcd = f & 7, loc = f >> 3;
    const int b  = xcd * 8 + (loc >> 4);
    const int ct = loc & 15, c0 = ct * 32;
    const int tid = threadIdx.x, w = tid >> 6, lane = tid & 63;
    const int l5 = lane & 31, hi = lane >> 5;
    const ush* Qb  = QUf + (size_t)b * 131072;
    const ush* Kb  = KUf + (size_t)b * 131072;
    const ush* Vbb = Vbf + (size_t)b * 65536;
    const size_t obase = (size_t)b * (ND * NL);

    // ---- Phase A: alpha (rows all 512 l, cols c0..c0+31), exp -> Pt ----
    const ush* kbase = Kb + (size_t)ct * 8192 + lane * 8;   // KU rows c0..+31
    #pragma unroll
    for (int t = 0; t < 4; ++t) {
        const int base = t * 128 + w * 32;
        const ush* qp = Qb + (size_t)(t * 4 + w) * 8192 + lane * 8;
        f32x16 a0 = zero16(), a1 = zero16();
        #pragma unroll
        for (int ks = 0; ks < 16; ks += 2) {
            a0 = __builtin_amdgcn_mfma_f32_32x32x16_bf16(*(const short8*)(qp + ks * 512),
                     *(const short8*)(kbase + ks * 512), a0, 0, 0, 0);
            a1 = __builtin_amdgcn_mfma_f32_32x32x16_bf16(*(const short8*)(qp + (ks + 1) * 512),
                     *(const short8*)(kbase + (ks + 1) * 512), a1, 0, 0, 0);
        }
        // exp, pack row-pairs, write Pt[c=l5][l]
        #pragma unroll
        for (int q = 0; q < 8; ++q) {
            int r6 = q * 2;
            int l = base + (r6 & 3) + 8 * (r6 >> 2) + 4 * hi;   // even
            float e0 = __expf(a0[r6] + a1[r6]);
            float e1 = __expf(a0[r6 + 1] + a1[r6 + 1]);
            unsigned int pk = (unsigned int)f2bs(e0) | ((unsigned int)f2bs(e1) << 16);
            *(unsigned int*)(Pt + l5 * PT_PITCH + l * 2) = pk;
        }
    }
    __syncthreads();

    // ---- row partial sums over this block's 32 cols -> dAcc[b][l] ----
    {
        int l = tid * 2;   // rows l, l+1
        float s0 = 0.f, s1 = 0.f;
        #pragma unroll 8
        for (int c = 0; c < 32; ++c) {
            unsigned int u = *(const unsigned int*)(Pt + c * PT_PITCH + l * 2);
            union { unsigned int i; float v; } lo, hic;
            lo.i = u << 16; hic.i = u & 0xFFFF0000u;
            s0 += lo.v; s1 += hic.v;
        }
        atomicAdd(dAcc + b * NL + l, s0);
        atomicAdd(dAcc + b * NL + l + 1, s1);
    }

    cooperative_groups::this_grid().sync();

    // ---- Phase B: out[d][c] = (sum_l Vv[d][l] * N[l][c]) / denom[c] ----
    const float rd = 1.0f / dAcc[b * NL + c0 + l5];
    f32x16 acc0 = zero16(), acc1 = zero16();
    const ush* vp = Vbb + (size_t)w * 16384 + lane * 8;
    #pragma unroll
    for (int ks = 0; ks < 32; ks += 2) {
        short8 pb0 = *(const short8*)(Pt + l5 * PT_PITCH + (ks * 16 + hi * 8) * 2);
        acc0 = __builtin_amdgcn_mfma_f32_32x32x16_bf16(*(const short8*)(vp + ks * 512), pb0, acc0, 0, 0, 0);
        short8 pb1 = *(const short8*)(Pt + l5 * PT_PITCH + ((ks + 1) * 16 + hi * 8) * 2);
        acc1 = __builtin_amdgcn_mfma_f32_32x32x16_bf16(*(const short8*)(vp + (ks + 1) * 512), pb1, acc1, 0, 0, 0);
    }
    f32x16 acc = acc0 + acc1;
    #pragma unroll
    for (int r6 = 0; r6 < 16; ++r6) {
        int d = w * 32 + (r6 & 3) + 8 * (r6 >> 2) + 4 * hi;
        out[obase + (size_t)d * NL + c0 + l5] = acc[r6] * rd;
    }
}

// ---------------- Fallback A: N = exp(alpha) + partial row sums (R9-proven) ----------------
__global__ __launch_bounds__(256) void alpha_kernel(
    const ush* __restrict__ QUf, const ush* __restrict__ KUf,
    ush* __restrict__ Nf, float* __restrict__ dPart)
{
    __shared__ float red[4][2][16];
    __shared__ ush TlsA[4][2048];
    const int f = blockIdx.x;
    const int xcd = f & 7, loc = f >> 3;
    const int b  = xcd * 8 + (loc >> 5);
    const int rt = (loc >> 1) & 15;
    const int ch = loc & 1;
    const int tid = threadIdx.x, w = tid >> 6, lane = tid & 63;
    const int l5 = lane & 31, hi = lane >> 5;
    const ush* Qb = QUf + (size_t)b * 131072;
    const ush* Kb = KUf + (size_t)b * 131072;
    ush* Nfb = Nf + (size_t)b * 262144;

    const ush* qp = Qb + (size_t)rt * 8192 + lane * 8;
    const int cpg0 = ch * 8 + w * 2;

    f32x16 a0[2], a1[2];
    a0[0] = zero16(); a0[1] = zero16(); a1[0] = zero16(); a1[1] = zero16();
    #pragma unroll
    for (int ks = 0; ks < 16; ks += 2) {
        short8 aqa = *(const short8*)(qp + ks * 512);
        short8 aqb = *(const short8*)(qp + (ks + 1) * 512);
        #pragma unroll
        for (int cp = 0; cp < 2; ++cp) {
            const ush* kp = Kb + (size_t)((cpg0 + cp) * 16) * 512 + lane * 8;
            a0[cp] = __builtin_amdgcn_mfma_f32_32x32x16_bf16(aqa,
                         *(const short8*)(kp + ks * 512), a0[cp], 0, 0, 0);
            a1[cp] = __builtin_amdgcn_mfma_f32_32x32x16_bf16(aqb,
                         *(const short8*)(kp + (ks + 1) * 512), a1[cp], 0, 0, 0);
        }
    }

    float rs[16];
    #pragma unroll
    for (int r6 = 0; r6 < 16; ++r6) rs[r6] = 0.f;
    char* Tc = (char*)TlsA[w];
    #pragma unroll
    for (int cp = 0; cp < 2; ++cp) {
        const int cpg = cpg0 + cp;
        float e[16];
        #pragma unroll
        for (int r6 = 0; r6 < 16; ++r6) {
            e[r6] = __expf(a0[cp][r6] + a1[cp][r6]);
            rs[r6] += e[r6];
        }
        #pragma unroll
        for (int q = 0; q < 8; ++q) {
            int r6 = q * 2;
            int r = (r6 & 3) + 8 * (r6 >> 2) + 4 * hi;
            unsigned int pk = (unsigned int)f2bs(e[r6])
                            | ((unsigned int)f2bs(e[r6 + 1]) << 16);
            *(unsigned int*)(Tc + l5 * 128 + ((r * 2) ^ ((l5 & 7) << 4))) = pk;
        }
        #pragma unroll
        for (int ksl = 0; ksl < 2; ++ksl) {
            short8 v = *(const short8*)(Tc + l5 * 128 +
                           (((ksl * 16 + hi * 8) * 2) ^ ((l5 & 7) << 4)));
            int ksg = rt * 2 + ksl;
            *(short8*)(Nfb + ((size_t)(cpg * 32 + ksg) * 64 + lane) * 8) = v;
        }
    }

    #pragma unroll
    for (int mk = 1; mk <= 16; mk <<= 1)
        #pragma unroll
        for (int r6 = 0; r6 < 16; ++r6) rs[r6] += __shfl_xor(rs[r6], mk, 32);
    if (l5 == 0)
        #pragma unroll
        for (int r6 = 0; r6 < 16; ++r6) red[w][hi][r6] = rs[r6];
    __syncthreads();
    if (tid < 32) {
        int t = tid;
        int hh = (t >> 2) & 1, r6 = (t & 3) + 4 * (t >> 3);
        float s = red[0][hh][r6] + red[1][hh][r6] + red[2][hh][r6] + red[3][hh][r6];
        dPart[((size_t)b * 2 + ch) * NL + rt * 32 + t] = s;
    }
}

// ---------------- Fallback B: out = (Vv @ N) / (dPart0 + dPart1) ----------------
__global__ __launch_bounds__(256) void pv_kernel(
    const ush* __restrict__ Vbf, const ush* __restrict__ Nf,
    const float* __restrict__ dPart, float* __restrict__ out)
{
    const int f = blockIdx.x;
    const int xcd = f & 7, loc = f >> 3;
    const int b  = xcd * 8 + (loc >> 4);
    const int ct = loc & 15;
    const int tid = threadIdx.x, w = tid >> 6, lane = tid & 63;
    const int l5 = lane & 31, hi = lane >> 5;
    const ush* Vbb = Vbf + (size_t)b * 65536;
    const ush* Nfb = Nf + (size_t)b * 262144;
    const size_t obase = (size_t)b * (ND * NL);

    const ush* vp = Vbb + (size_t)w * 16384 + lane * 8;
    const ush* np = Nfb + (size_t)ct * 16384 + lane * 8;

    f32x16 acc0 = zero16(), acc1 = zero16();
    #pragma unroll
    for (int ks = 0; ks < 32; ks += 2) {
        acc0 = __builtin_amdgcn_mfma_f32_32x32x16_bf16(*(const short8*)(vp + ks * 512),
                   *(const short8*)(np + ks * 512), acc0, 0, 0, 0);
        acc1 = __builtin_amdgcn_mfma_f32_32x32x16_bf16(*(const short8*)(vp + (ks + 1) * 512),
                   *(const short8*)(np + (ks + 1) * 512), acc1, 0, 0, 0);
    }
    f32x16 acc = acc0 + acc1;
    const int c0 = ct * 32;
    float rd = 1.0f / (dPart[((size_t)b * 2 + 0) * NL + c0 + l5]
                     + dPart[((size_t)b * 2 + 1) * NL + c0 + l5]);
    #pragma unroll
    for (int r6 = 0; r6 < 16; ++r6) {
        int d = w * 32 + (r6 & 3) + 8 * (r6 >> 2) + 4 * hi;
        out[obase + (size_t)d * NL + c0 + l5] = acc[r6] * rd;
    }
}

// ---------------- Fallback small-ws: fused denom + result (recomputes alpha) ----------------
__global__ __launch_bounds__(256) void fused_kernel(
    const ush* __restrict__ QUf, const ush* __restrict__ KUf,
    const ush* __restrict__ Vbf, float* __restrict__ out)
{
    __shared__ ush Pt2[32 * 136];
    __shared__ float red[128];
    __shared__ float rdenS[32];
    const int f = blockIdx.x;
    const int xcd = f & 7, loc = f >> 3;
    const int b  = xcd * 8 + (loc >> 4);
    const int ct = loc & 15, c0 = ct * 32;
    const int tid = threadIdx.x, w = tid >> 6, lane = tid & 63;
    const int l5 = lane & 31, hi = lane >> 5;
    const ush* Qb  = QUf + (size_t)b * 131072;
    const ush* Kb  = KUf + (size_t)b * 131072;
    const ush* Vbb = Vbf + (size_t)b * 65536;
    const size_t obase = (size_t)b * (ND * NL);

    {
        short8 aq[16];
        const ush* qp = Qb + (size_t)ct * 8192 + lane * 8;
        #pragma unroll
        for (int ks = 0; ks < 16; ++ks) aq[ks] = *(const short8*)(qp + ks * 512);
        float rs[16];
        #pragma unroll
        for (int r = 0; r < 16; ++r) rs[r] = 0.f;
        #pragma unroll
        for (int t = 0; t < 4; ++t) {
            const ush* kp = Kb + (size_t)(w * 4 + t) * 8192 + lane * 8;
            f32x16 a0 = zero16(), a1 = zero16();
            #pragma unroll
            for (int ks = 0; ks < 16; ks += 2) {
                a0 = __builtin_amdgcn_mfma_f32_32x32x16_bf16(aq[ks],     *(const short8*)(kp + ks * 512),       a0, 0, 0, 0);
                a1 = __builtin_amdgcn_mfma_f32_32x32x16_bf16(aq[ks + 1], *(const short8*)(kp + (ks + 1) * 512), a1, 0, 0, 0);
            }
            #pragma unroll
            for (int r = 0; r < 16; ++r) rs[r] += __expf(a0[r] + a1[r]);
        }
        #pragma unroll
        for (int mk = 1; mk <= 16; mk <<= 1)
            #pragma unroll
            for (int r = 0; r < 16; ++r) rs[r] += __shfl_xor(rs[r], mk, 32);
        if (l5 == 0)
            #pragma unroll
            for (int r = 0; r < 16; ++r) red[(w * 2 + hi) * 16 + r] = rs[r];
    }
    __syncthreads();
    if (tid < 32) {
        int c = tid;
        int h2 = (c >> 2) & 1, r = (c & 3) + 4 * (c >> 3);
        float s = 0.f;
        #pragma unroll
        for (int kh = 0; kh < 4; ++kh) s += red[(kh * 2 + h2) * 16 + r];
        rdenS[c] = 1.0f / s;
    }
    __syncthreads();

    const int p2 = w;
    const float rden = rdenS[l5];
    const ush* kp2 = Kb + (size_t)ct * 8192 + lane * 8;
    f32x16 oA = zero16(), oB = zero16();

    for (int it = 0; it < 4; ++it) {
        if (it) __syncthreads();
        const ush* qp2 = Qb + (size_t)(it * 4 + p2) * 8192 + lane * 8;
        f32x16 s0 = zero16(), s1 = zero16();
        #pragma unroll
        for (int ks = 0; ks < 16; ks += 2) {
            s0 = __builtin_amdgcn_mfma_f32_32x32x16_bf16(*(const short8*)(qp2 + ks * 512),
                                                         *(const short8*)(kp2 + ks * 512),       s0, 0, 0, 0);
            s1 = __builtin_amdgcn_mfma_f32_32x32x16_bf16(*(const short8*)(qp2 + (ks + 1) * 512),
                                                         *(const short8*)(kp2 + (ks + 1) * 512), s1, 0, 0, 0);
        }
        #pragma unroll
        for (int q = 0; q < 4; ++q) {
            ushort4 pv;
            pv.x = f2bs(__expf(s0[q * 4 + 0] + s1[q * 4 + 0]) * rden);
            pv.y = f2bs(__expf(s0[q * 4 + 1] + s1[q * 4 + 1]) * rden);
            pv.z = f2bs(__expf(s0[q * 4 + 2] + s1[q * 4 + 2]) * rden);
            pv.w = f2bs(__expf(s0[q * 4 + 3] + s1[q * 4 + 3]) * rden);
            int boff = l5 * 272 + (((p2 * 32 + q * 8 + hi * 4) * 2) ^ ((l5 & 7) << 4));
            *(ushort4*)((char*)Pt2 + boff) = pv;
        }
        __syncthreads();
        #pragma unroll
        for (int j = 0; j < 8; j += 2) {
            short8 va0 = *(const short8*)(Vbb + ((size_t)(p2 * 32 + it * 8 + j) * 64 + lane) * 8);
            short8 pb0 = *(const short8*)((char*)Pt2 + l5 * 272 + (((j * 16 + hi * 8) * 2) ^ ((l5 & 7) << 4)));
            oA = __builtin_amdgcn_mfma_f32_32x32x16_bf16(va0, pb0, oA, 0, 0, 0);
            short8 va1 = *(const short8*)(Vbb + ((size_t)(p2 * 32 + it * 8 + j + 1) * 64 + lane) * 8);
            short8 pb1 = *(const short8*)((char*)Pt2 + l5 * 272 + ((((j + 1) * 16 + hi * 8) * 2) ^ ((l5 & 7) << 4)));
            oB = __builtin_amdgcn_mfma_f32_32x32x16_bf16(va1, pb1, oB, 0, 0, 0);
        }
    }
    f32x16 oacc = oA + oB;
    #pragma unroll
    for (int r = 0; r < 16; ++r) {
        int d = p2 * 32 + (r & 3) + 8 * (r >> 2) + 4 * hi;
        out[obase + (size_t)d * NL + c0 + l5] = oacc[r];
    }
}

extern "C" void kernel_launch(void* const* d_in, const int* in_sizes, int n_in,
                              void* d_out, int out_size, void* d_ws, size_t ws_size,
                              hipStream_t stream)
{
    const float* EW   = (const float*)d_in[0];
    const float* ES   = (const float*)d_in[1];
    const float* WQ_w = (const float*)d_in[2];
    const float* WQ_b = (const float*)d_in[3];
    const float* WK_w = (const float*)d_in[4];
    const float* WK_b = (const float*)d_in[5];
    const float* UQ_w = (const float*)d_in[6];
    const float* UQ_b = (const float*)d_in[7];
    const float* UK_w = (const float*)d_in[8];
    const float* UK_b = (const float*)d_in[9];
    const float* V_w  = (const float*)d_in[10];
    const float* V_b  = (const float*)d_in[11];

    // ws: QUf 16MB | KUf 16MB | Vbf 8MB | Wb 160KB | dAcc/dPart 512KB @40.5MB | Nf 32MB @41MB
    if (ws_size < (size_t)41 * 1024 * 1024) return;

    char* ws = (char*)d_ws;
    ush* QUf = (ush*)ws;
    ush* KUf = (ush*)(ws + (size_t)16 * 1024 * 1024);
    ush* Vbf = (ush*)(ws + (size_t)32 * 1024 * 1024);
    ush* Wb  = (ush*)(ws + (size_t)40 * 1024 * 1024);
    float* dAcc = (float*)(ws + (size_t)40 * 1024 * 1024 + 512 * 1024);
    ush* Nf  = (ush*)(ws + (size_t)41 * 1024 * 1024);
    float* outp = (float*)d_out;

    wconv_kernel<<<dim3(16, 5), 256, 0, stream>>>(WQ_w, WK_w, UQ_w, UK_w, V_w, Wb);
    projqk_kernel<<<1024, 256, 0, stream>>>(EW, ES, Wb,
                                            WQ_b, WK_b, UQ_b, UK_b, QUf, KUf);
    projv_kernel<<<256, 256, 0, stream>>>(EW, Wb, V_b, Vbf);

    if (ws_size >= (size_t)74 * 1024 * 1024) {
        hipError_t err = hipMemsetAsync(dAcc, 0, (size_t)NB * NL * sizeof(float), stream);
        if (err == hipSuccess) {
            void* args[] = { (void*)&QUf, (void*)&KUf, (void*)&Vbf, (void*)&dAcc, (void*)&outp };
            err = hipLaunchCooperativeKernel((const void*)coop_kernel,
                                             dim3(1024), dim3(256), args, 0, stream);
        }
        if (err != hipSuccess) {
            // fallback: proven two-kernel path (Nf materialized)
            alpha_kernel<<<2048, 256, 0, stream>>>(QUf, KUf, Nf, dAcc);
            pv_kernel<<<1024, 256, 0, stream>>>(Vbf, Nf, dAcc, outp);
        }
    } else {
        fused_kernel<<<1024, 256, 0, stream>>>(QUf, KUf, Vbf, outp);
    }
}

// Round 15
// 88.771 us; speedup vs baseline: 1.5444x; 1.5444x over previous
//
#include <hip/hip_runtime.h>
#include <hip/hip_bf16.h>

#define NB 64
#define NL 512
#define ND 128
#define NK 256   // concat(Q,UQ) contraction dim

typedef unsigned short ush;
typedef __attribute__((ext_vector_type(8))) short short8;
typedef __attribute__((ext_vector_type(16))) float f32x16;

// Fragment layouts (bf16), one 32x32x16-MFMA operand chunk per lane:
//  QU_f/KU_f: elem off = ((p*16 + ks)*64 + lane)*8 ; holds row p*32+(lane&31),
//             k = ks*16+(lane>>5)*8 .. +7.  p GLOBAL row-panel (batch*16 + local).
//  Vb_f:      elem off = ((p*32 + ks)*64 + lane)*8 ; holds Vv row p*32+(lane&31),
//             l = ks*16+(lane>>5)*8 .. +7.  p GLOBAL (= rt).
//  N_f:       elem off = ((cp*32 + ks)*64 + lane)*8 ; holds N col cp*32+(lane&31),
//             l = ks*16+(lane>>5)*8 .. +7.  cp batch-local [0,16), ks [0,32).

__device__ __forceinline__ ush f2bs(float f) {
    union { __hip_bfloat16 h; ush u; } cv;
    cv.h = __float2bfloat16(f);
    return cv.u;
}
__device__ __forceinline__ short8 pack_bf8(float4 a, float4 b) {
    short8 r;
    r[0] = (short)f2bs(a.x); r[1] = (short)f2bs(a.y);
    r[2] = (short)f2bs(a.z); r[3] = (short)f2bs(a.w);
    r[4] = (short)f2bs(b.x); r[5] = (short)f2bs(b.y);
    r[6] = (short)f2bs(b.z); r[7] = (short)f2bs(b.w);
    return r;
}
__device__ __forceinline__ f32x16 zero16() {
    f32x16 z = {0.f,0.f,0.f,0.f,0.f,0.f,0.f,0.f,0.f,0.f,0.f,0.f,0.f,0.f,0.f,0.f};
    return z;
}

// ---------------- Kernel W: convert 5 weight matrices to bf16 ----------------
__global__ __launch_bounds__(256) void wconv_kernel(
    const float* __restrict__ W0, const float* __restrict__ W1,
    const float* __restrict__ W2, const float* __restrict__ W3,
    const float* __restrict__ W4, ush* __restrict__ Wb)
{
    const int m = blockIdx.y;
    const float* W = (m == 0) ? W0 : (m == 1) ? W1 : (m == 2) ? W2 : (m == 3) ? W3 : W4;
    const int e = (blockIdx.x * 256 + threadIdx.x) * 4;
    float4 v = *(const float4*)(W + e);
    ushort4 o;
    o.x = f2bs(v.x); o.y = f2bs(v.y); o.z = f2bs(v.z); o.w = f2bs(v.w);
    *(ushort4*)(Wb + m * 16384 + e) = o;
}

// ---------------- Kernel PQK: Q/K/UQ/UK projections -> fragment outputs ----------------
// 1D grid 1024 = 8 XCD x 128; rt = xcd*32 + (loc>>2), m = loc&3.
// Runs LAST among producers so QUf/KUf are freshest in L2 for alpha.
__global__ __launch_bounds__(256) void projqk_kernel(
    const float* __restrict__ EW, const float* __restrict__ ES,
    const ush* __restrict__ Wb,
    const float* __restrict__ b0, const float* __restrict__ b1,
    const float* __restrict__ b2, const float* __restrict__ b3,
    ush* __restrict__ QUf, ush* __restrict__ KUf)
{
    __shared__ ush Tls[4][2048];
    const int f = blockIdx.x;
    const int xcd = f & 7, loc = f >> 3;
    const int rt = xcd * 32 + (loc >> 2);
    const int m  = loc & 3;
    const int tid = threadIdx.x, w = tid >> 6, lane = tid & 63;
    const int l5 = lane & 31, hi = lane >> 5;
    const float* X = (m >= 2) ? ES : EW;
    const int rbase = rt * 128 + w * 32;

    const float* xr = X + (size_t)(rbase + l5) * ND + hi * 8;
    short8 af[8];
    #pragma unroll
    for (int ks = 0; ks < 8; ++ks)
        af[ks] = pack_bf8(*(const float4*)(xr + ks * 16),
                          *(const float4*)(xr + ks * 16 + 4));

    const ush* Wm = Wb + m * 16384;
    const float* Bp = (m == 0) ? b0 : (m == 1) ? b1 : (m == 2) ? b2 : b3;
    const float scl = 0.044194173824159216f;  // 1/(2*sqrt(128))

    char* Tc = (char*)Tls[w];
    ush* dstf = (m == 0 || m == 2) ? QUf : KUf;
    const int ko = (m >= 2) ? 8 : 0;
    const int p_g = rt * 4 + w;

    #pragma unroll
    for (int pass = 0; pass < 2; ++pass) {
        f32x16 acc[2];
        acc[0] = zero16(); acc[1] = zero16();
        #pragma unroll
        for (int ks = 0; ks < 8; ++ks) {
            #pragma unroll
            for (int nbl = 0; nbl < 2; ++nbl) {
                const int nb = pass * 2 + nbl;
                short8 bf_ = *(const short8*)(Wm + (nb * 32 + l5) * 128 + ks * 16 + hi * 8);
                acc[nbl] = __builtin_amdgcn_mfma_f32_32x32x16_bf16(af[ks], bf_, acc[nbl], 0, 0, 0);
            }
        }
        #pragma unroll
        for (int nbl = 0; nbl < 2; ++nbl) {
            const int nb = pass * 2 + nbl;
            float bias = Bp[nb * 32 + l5];
            #pragma unroll
            for (int r6 = 0; r6 < 16; ++r6) {
                int row = (r6 & 3) + 8 * (r6 >> 2) + 4 * hi;
                int boff = row * 128 + (((nbl * 32 + l5) * 2) ^ ((row & 7) << 4));
                *(ush*)(Tc + boff) = f2bs((acc[nbl][r6] + bias) * scl);
            }
        }
        #pragma unroll
        for (int ks8 = 0; ks8 < 4; ++ks8) {
            int boff = l5 * 128 + ((ks8 * 32 + hi * 16) ^ ((l5 & 7) << 4));
            short8 v = *(const short8*)(Tc + boff);
            int ksg = ko + pass * 4 + ks8;
            *(short8*)(dstf + ((size_t)(p_g * 16 + ksg) * 64 + lane) * 8) = v;
        }
    }
}

// ---------------- Kernel PV: V projection -> Vv fragment output ----------------
// 1D grid 256 = 8 XCD x 32; rt = (f&7)*32 + (f>>3). Runs BEFORE projqk.
__global__ __launch_bounds__(256) void projv_kernel(
    const float* __restrict__ EW, const ush* __restrict__ Wb,
    const float* __restrict__ b4, ush* __restrict__ Vbf)
{
    __shared__ ush lds[16384];
    const int f = blockIdx.x;
    const int rt = (f & 7) * 32 + (f >> 3);
    const int tid = threadIdx.x, w = tid >> 6, lane = tid & 63;
    const int l5 = lane & 31, hi = lane >> 5;
    const int rbase = rt * 128 + w * 32;

    const float* xr = EW + (size_t)(rbase + l5) * ND + hi * 8;
    short8 af[8];
    #pragma unroll
    for (int ks = 0; ks < 8; ++ks)
        af[ks] = pack_bf8(*(const float4*)(xr + ks * 16),
                          *(const float4*)(xr + ks * 16 + 4));

    const ush* Wm = Wb + 4 * 16384;
    f32x16 acc[4];
    acc[0] = zero16(); acc[1] = zero16(); acc[2] = zero16(); acc[3] = zero16();
    #pragma unroll
    for (int ks = 0; ks < 8; ++ks) {
        #pragma unroll
        for (int nb = 0; nb < 4; ++nb) {
            short8 bf_ = *(const short8*)(Wm + (nb * 32 + l5) * 128 + ks * 16 + hi * 8);
            acc[nb] = __builtin_amdgcn_mfma_f32_32x32x16_bf16(af[ks], bf_, acc[nb], 0, 0, 0);
        }
    }

    char* Lc = (char*)lds;
    #pragma unroll
    for (int nb = 0; nb < 4; ++nb) {
        float bias = b4[nb * 32 + l5];
        #pragma unroll
        for (int r6 = 0; r6 < 16; ++r6) {
            int row5 = (r6 & 3) + 8 * (r6 >> 2) + 4 * hi;
            int dl = w * 8 + (row5 >> 2);
            int lcol = (row5 & 3) * 128 + nb * 32 + l5;
            int boff = dl * 1024 + ((lcol * 2) ^ ((dl & 7) << 4));
            *(ush*)(Lc + boff) = f2bs(acc[nb][r6] + bias);
        }
    }
    __syncthreads();
    #pragma unroll
    for (int it = 0; it < 8; ++it) {
        int chunk = it * 256 + tid;
        int ks = chunk >> 6, ln = chunk & 63;
        int l5b = ln & 31, hib = ln >> 5;
        int boff = l5b * 1024 + ((ks * 32 + hib * 16) ^ ((l5b & 7) << 4));
        short8 v = *(const short8*)(Lc + boff);
        *(short8*)(Vbf + ((size_t)(rt * 32 + ks) * 64 + ln) * 8) = v;
    }
}

// ---------------- Kernel A: N = exp(alpha) + partial row sums ----------------
// 1D grid 2048 = 8 XCD x 256; b = xcd*8 + (loc>>5), rt = (loc>>1)&15, ch = loc&1.
// Nf stores are NON-TEMPORAL: written once, read once by pv -> keep L2 for QU/KU.
__global__ __launch_bounds__(256) void alpha_kernel(
    const ush* __restrict__ QUf, const ush* __restrict__ KUf,
    ush* __restrict__ Nf, float* __restrict__ dPart)
{
    __shared__ float red[4][2][16];
    __shared__ ush TlsA[4][2048];
    const int f = blockIdx.x;
    const int xcd = f & 7, loc = f >> 3;
    const int b  = xcd * 8 + (loc >> 5);
    const int rt = (loc >> 1) & 15;
    const int ch = loc & 1;
    const int tid = threadIdx.x, w = tid >> 6, lane = tid & 63;
    const int l5 = lane & 31, hi = lane >> 5;
    const ush* Qb = QUf + (size_t)b * 131072;
    const ush* Kb = KUf + (size_t)b * 131072;
    ush* Nfb = Nf + (size_t)b * 262144;

    const ush* qp = Qb + (size_t)rt * 8192 + lane * 8;
    const int cpg0 = ch * 8 + w * 2;

    f32x16 a0[2], a1[2];
    a0[0] = zero16(); a0[1] = zero16(); a1[0] = zero16(); a1[1] = zero16();
    #pragma unroll
    for (int ks = 0; ks < 16; ks += 2) {
        short8 aqa = *(const short8*)(qp + ks * 512);
        short8 aqb = *(const short8*)(qp + (ks + 1) * 512);
        #pragma unroll
        for (int cp = 0; cp < 2; ++cp) {
            const ush* kp = Kb + (size_t)((cpg0 + cp) * 16) * 512 + lane * 8;
            a0[cp] = __builtin_amdgcn_mfma_f32_32x32x16_bf16(aqa,
                         *(const short8*)(kp + ks * 512), a0[cp], 0, 0, 0);
            a1[cp] = __builtin_amdgcn_mfma_f32_32x32x16_bf16(aqb,
                         *(const short8*)(kp + (ks + 1) * 512), a1[cp], 0, 0, 0);
        }
    }

    float rs[16];
    #pragma unroll
    for (int r6 = 0; r6 < 16; ++r6) rs[r6] = 0.f;
    char* Tc = (char*)TlsA[w];
    #pragma unroll
    for (int cp = 0; cp < 2; ++cp) {
        const int cpg = cpg0 + cp;
        float e[16];
        #pragma unroll
        for (int r6 = 0; r6 < 16; ++r6) {
            e[r6] = __expf(a0[cp][r6] + a1[cp][r6]);
            rs[r6] += e[r6];
        }
        // transpose to N-frag: T[c][r], swizzle keyed by c (=l5); row-pairs as u32
        #pragma unroll
        for (int q = 0; q < 8; ++q) {
            int r6 = q * 2;
            int r = (r6 & 3) + 8 * (r6 >> 2) + 4 * hi;
            unsigned int pk = (unsigned int)f2bs(e[r6])
                            | ((unsigned int)f2bs(e[r6 + 1]) << 16);
            *(unsigned int*)(Tc + l5 * 128 + ((r * 2) ^ ((l5 & 7) << 4))) = pk;
        }
        #pragma unroll
        for (int ksl = 0; ksl < 2; ++ksl) {
            short8 v = *(const short8*)(Tc + l5 * 128 +
                           (((ksl * 16 + hi * 8) * 2) ^ ((l5 & 7) << 4)));
            int ksg = rt * 2 + ksl;
            __builtin_nontemporal_store(v,
                (short8*)(Nfb + ((size_t)(cpg * 32 + ksg) * 64 + lane) * 8));
        }
    }

    // partial row sums over this block's 256 cols -> dPart[b][ch][rt*32 + l]
    #pragma unroll
    for (int mk = 1; mk <= 16; mk <<= 1)
        #pragma unroll
        for (int r6 = 0; r6 < 16; ++r6) rs[r6] += __shfl_xor(rs[r6], mk, 32);
    if (l5 == 0)
        #pragma unroll
        for (int r6 = 0; r6 < 16; ++r6) red[w][hi][r6] = rs[r6];
    __syncthreads();
    if (tid < 32) {
        int t = tid;
        int hh = (t >> 2) & 1, r6 = (t & 3) + 4 * (t >> 3);
        float s = red[0][hh][r6] + red[1][hh][r6] + red[2][hh][r6] + red[3][hh][r6];
        dPart[((size_t)b * 2 + ch) * NL + rt * 32 + t] = s;
    }
}

// ---------------- Kernel B: out = (Vv @ N) / (dPart0 + dPart1) ----------------
// 1D grid 1024 = 8 XCD x 128; b = xcd*8 + (loc>>4), ct = loc&15 (32-col tiles).
// Nf loads and out stores are NON-TEMPORAL (streamed once).
__global__ __launch_bounds__(256) void pv_kernel(
    const ush* __restrict__ Vbf, const ush* __restrict__ Nf,
    const float* __restrict__ dPart, float* __restrict__ out)
{
    const int f = blockIdx.x;
    const int xcd = f & 7, loc = f >> 3;
    const int b  = xcd * 8 + (loc >> 4);
    const int ct = loc & 15;
    const int tid = threadIdx.x, w = tid >> 6, lane = tid & 63;
    const int l5 = lane & 31, hi = lane >> 5;
    const ush* Vbb = Vbf + (size_t)b * 65536;
    const ush* Nfb = Nf + (size_t)b * 262144;
    const size_t obase = (size_t)b * (ND * NL);

    const ush* vp = Vbb + (size_t)w * 16384 + lane * 8;
    const ush* np = Nfb + (size_t)ct * 16384 + lane * 8;

    f32x16 acc0 = zero16(), acc1 = zero16();
    #pragma unroll
    for (int ks = 0; ks < 32; ks += 2) {
        short8 nb0 = __builtin_nontemporal_load((const short8*)(np + ks * 512));
        acc0 = __builtin_amdgcn_mfma_f32_32x32x16_bf16(*(const short8*)(vp + ks * 512),
                   nb0, acc0, 0, 0, 0);
        short8 nb1 = __builtin_nontemporal_load((const short8*)(np + (ks + 1) * 512));
        acc1 = __builtin_amdgcn_mfma_f32_32x32x16_bf16(*(const short8*)(vp + (ks + 1) * 512),
                   nb1, acc1, 0, 0, 0);
    }
    f32x16 acc = acc0 + acc1;
    const int c0 = ct * 32;
    float rd = 1.0f / (dPart[((size_t)b * 2 + 0) * NL + c0 + l5]
                     + dPart[((size_t)b * 2 + 1) * NL + c0 + l5]);
    #pragma unroll
    for (int r6 = 0; r6 < 16; ++r6) {
        int d = w * 32 + (r6 & 3) + 8 * (r6 >> 2) + 4 * hi;
        __builtin_nontemporal_store(acc[r6] * rd,
            out + obase + (size_t)d * NL + c0 + l5);
    }
}

// ---------------- Fallback small-ws: fused denom + result (recomputes alpha) ----------------
__global__ __launch_bounds__(256) void fused_kernel(
    const ush* __restrict__ QUf, const ush* __restrict__ KUf,
    const ush* __restrict__ Vbf, float* __restrict__ out)
{
    __shared__ ush Pt2[32 * 136];
    __shared__ float red[128];
    __shared__ float rdenS[32];
    const int f = blockIdx.x;
    const int xcd = f & 7, loc = f >> 3;
    const int b  = xcd * 8 + (loc >> 4);
    const int ct = loc & 15, c0 = ct * 32;
    const int tid = threadIdx.x, w = tid >> 6, lane = tid & 63;
    const int l5 = lane & 31, hi = lane >> 5;
    const ush* Qb  = QUf + (size_t)b * 131072;
    const ush* Kb  = KUf + (size_t)b * 131072;
    const ush* Vbb = Vbf + (size_t)b * 65536;
    const size_t obase = (size_t)b * (ND * NL);

    {
        short8 aq[16];
        const ush* qp = Qb + (size_t)ct * 8192 + lane * 8;
        #pragma unroll
        for (int ks = 0; ks < 16; ++ks) aq[ks] = *(const short8*)(qp + ks * 512);
        float rs[16];
        #pragma unroll
        for (int r = 0; r < 16; ++r) rs[r] = 0.f;
        #pragma unroll
        for (int t = 0; t < 4; ++t) {
            const ush* kp = Kb + (size_t)(w * 4 + t) * 8192 + lane * 8;
            f32x16 a0 = zero16(), a1 = zero16();
            #pragma unroll
            for (int ks = 0; ks < 16; ks += 2) {
                a0 = __builtin_amdgcn_mfma_f32_32x32x16_bf16(aq[ks],     *(const short8*)(kp + ks * 512),       a0, 0, 0, 0);
                a1 = __builtin_amdgcn_mfma_f32_32x32x16_bf16(aq[ks + 1], *(const short8*)(kp + (ks + 1) * 512), a1, 0, 0, 0);
            }
            #pragma unroll
            for (int r = 0; r < 16; ++r) rs[r] += __expf(a0[r] + a1[r]);
        }
        #pragma unroll
        for (int mk = 1; mk <= 16; mk <<= 1)
            #pragma unroll
            for (int r = 0; r < 16; ++r) rs[r] += __shfl_xor(rs[r], mk, 32);
        if (l5 == 0)
            #pragma unroll
            for (int r = 0; r < 16; ++r) red[(w * 2 + hi) * 16 + r] = rs[r];
    }
    __syncthreads();
    if (tid < 32) {
        int c = tid;
        int h2 = (c >> 2) & 1, r = (c & 3) + 4 * (c >> 3);
        float s = 0.f;
        #pragma unroll
        for (int kh = 0; kh < 4; ++kh) s += red[(kh * 2 + h2) * 16 + r];
        rdenS[c] = 1.0f / s;
    }
    __syncthreads();

    const int p2 = w;
    const float rden = rdenS[l5];
    const ush* kp2 = Kb + (size_t)ct * 8192 + lane * 8;
    f32x16 oA = zero16(), oB = zero16();

    for (int it = 0; it < 4; ++it) {
        if (it) __syncthreads();
        const ush* qp2 = Qb + (size_t)(it * 4 + p2) * 8192 + lane * 8;
        f32x16 s0 = zero16(), s1 = zero16();
        #pragma unroll
        for (int ks = 0; ks < 16; ks += 2) {
            s0 = __builtin_amdgcn_mfma_f32_32x32x16_bf16(*(const short8*)(qp2 + ks * 512),
                                                         *(const short8*)(kp2 + ks * 512),       s0, 0, 0, 0);
            s1 = __builtin_amdgcn_mfma_f32_32x32x16_bf16(*(const short8*)(qp2 + (ks + 1) * 512),
                                                         *(const short8*)(kp2 + (ks + 1) * 512), s1, 0, 0, 0);
        }
        #pragma unroll
        for (int q = 0; q < 4; ++q) {
            ushort4 pv;
            pv.x = f2bs(__expf(s0[q * 4 + 0] + s1[q * 4 + 0]) * rden);
            pv.y = f2bs(__expf(s0[q * 4 + 1] + s1[q * 4 + 1]) * rden);
            pv.z = f2bs(__expf(s0[q * 4 + 2] + s1[q * 4 + 2]) * rden);
            pv.w = f2bs(__expf(s0[q * 4 + 3] + s1[q * 4 + 3]) * rden);
            int boff = l5 * 272 + (((p2 * 32 + q * 8 + hi * 4) * 2) ^ ((l5 & 7) << 4));
            *(ushort4*)((char*)Pt2 + boff) = pv;
        }
        __syncthreads();
        #pragma unroll
        for (int j = 0; j < 8; j += 2) {
            short8 va0 = *(const short8*)(Vbb + ((size_t)(p2 * 32 + it * 8 + j) * 64 + lane) * 8);
            short8 pb0 = *(const short8*)((char*)Pt2 + l5 * 272 + (((j * 16 + hi * 8) * 2) ^ ((l5 & 7) << 4)));
            oA = __builtin_amdgcn_mfma_f32_32x32x16_bf16(va0, pb0, oA, 0, 0, 0);
            short8 va1 = *(const short8*)(Vbb + ((size_t)(p2 * 32 + it * 8 + j + 1) * 64 + lane) * 8);
            short8 pb1 = *(const short8*)((char*)Pt2 + l5 * 272 + ((((j + 1) * 16 + hi * 8) * 2) ^ ((l5 & 7) << 4)));
            oB = __builtin_amdgcn_mfma_f32_32x32x16_bf16(va1, pb1, oB, 0, 0, 0);
        }
    }
    f32x16 oacc = oA + oB;
    #pragma unroll
    for (int r = 0; r < 16; ++r) {
        int d = p2 * 32 + (r & 3) + 8 * (r >> 2) + 4 * hi;
        out[obase + (size_t)d * NL + c0 + l5] = oacc[r];
    }
}

extern "C" void kernel_launch(void* const* d_in, const int* in_sizes, int n_in,
                              void* d_out, int out_size, void* d_ws, size_t ws_size,
                              hipStream_t stream)
{
    const float* EW   = (const float*)d_in[0];
    const float* ES   = (const float*)d_in[1];
    const float* WQ_w = (const float*)d_in[2];
    const float* WQ_b = (const float*)d_in[3];
    const float* WK_w = (const float*)d_in[4];
    const float* WK_b = (const float*)d_in[5];
    const float* UQ_w = (const float*)d_in[6];
    const float* UQ_b = (const float*)d_in[7];
    const float* UK_w = (const float*)d_in[8];
    const float* UK_b = (const float*)d_in[9];
    const float* V_w  = (const float*)d_in[10];
    const float* V_b  = (const float*)d_in[11];

    // ws: QUf 16MB | KUf 16MB | Vbf 8MB | Wb 160KB | dPart 512KB @40.5MB | Nf 32MB @41MB
    if (ws_size < (size_t)41 * 1024 * 1024) return;

    char* ws = (char*)d_ws;
    ush* QUf = (ush*)ws;
    ush* KUf = (ush*)(ws + (size_t)16 * 1024 * 1024);
    ush* Vbf = (ush*)(ws + (size_t)32 * 1024 * 1024);
    ush* Wb  = (ush*)(ws + (size_t)40 * 1024 * 1024);
    float* dPart = (float*)(ws + (size_t)40 * 1024 * 1024 + 512 * 1024);
    ush* Nf  = (ush*)(ws + (size_t)41 * 1024 * 1024);
    float* outp = (float*)d_out;

    // Order: projv BEFORE projqk so QUf/KUf are the freshest L2 data when alpha runs.
    wconv_kernel<<<dim3(16, 5), 256, 0, stream>>>(WQ_w, WK_w, UQ_w, UK_w, V_w, Wb);
    projv_kernel<<<256, 256, 0, stream>>>(EW, Wb, V_b, Vbf);
    projqk_kernel<<<1024, 256, 0, stream>>>(EW, ES, Wb,
                                            WQ_b, WK_b, UQ_b, UK_b, QUf, KUf);
    if (ws_size >= (size_t)74 * 1024 * 1024) {
        alpha_kernel<<<2048, 256, 0, stream>>>(QUf, KUf, Nf, dPart);
        pv_kernel<<<1024, 256, 0, stream>>>(Vbf, Nf, dPart, outp);
    } else {
        fused_kernel<<<1024, 256, 0, stream>>>(QUf, KUf, Vbf, outp);
    }
}

// Round 16
// 84.998 us; speedup vs baseline: 1.6130x; 1.0444x over previous
//
#include <hip/hip_runtime.h>
#include <hip/hip_bf16.h>

#define NB 64
#define NL 512
#define ND 128
#define NK 256   // concat(Q,UQ) contraction dim

typedef unsigned short ush;
typedef __attribute__((ext_vector_type(8))) short short8;
typedef __attribute__((ext_vector_type(16))) float f32x16;

// Fragment layouts (bf16), one 32x32x16-MFMA operand chunk per lane:
//  QU_f/KU_f: elem off = ((p*16 + ks)*64 + lane)*8 ; holds row p*32+(lane&31),
//             k = ks*16+(lane>>5)*8 .. +7.  p GLOBAL row-panel (batch*16 + local).
//  Vb_f:      elem off = ((p*32 + ks)*64 + lane)*8 ; holds Vv row p*32+(lane&31),
//             l = ks*16+(lane>>5)*8 .. +7.  p GLOBAL (= rt).
//  N_f:       elem off = ((cp*32 + ks)*64 + lane)*8 ; holds N col cp*32+(lane&31),
//             l = ks*16+(lane>>5)*8 .. +7.  cp batch-local [0,16), ks [0,32).

__device__ __forceinline__ ush f2bs(float f) {
    union { __hip_bfloat16 h; ush u; } cv;
    cv.h = __float2bfloat16(f);
    return cv.u;
}
__device__ __forceinline__ short8 pack_bf8(float4 a, float4 b) {
    short8 r;
    r[0] = (short)f2bs(a.x); r[1] = (short)f2bs(a.y);
    r[2] = (short)f2bs(a.z); r[3] = (short)f2bs(a.w);
    r[4] = (short)f2bs(b.x); r[5] = (short)f2bs(b.y);
    r[6] = (short)f2bs(b.z); r[7] = (short)f2bs(b.w);
    return r;
}
__device__ __forceinline__ f32x16 zero16() {
    f32x16 z = {0.f,0.f,0.f,0.f,0.f,0.f,0.f,0.f,0.f,0.f,0.f,0.f,0.f,0.f,0.f,0.f};
    return z;
}

// ---------------- Kernel W: convert 5 weight matrices to bf16 ----------------
__global__ __launch_bounds__(256) void wconv_kernel(
    const float* __restrict__ W0, const float* __restrict__ W1,
    const float* __restrict__ W2, const float* __restrict__ W3,
    const float* __restrict__ W4, ush* __restrict__ Wb)
{
    const int m = blockIdx.y;
    const float* W = (m == 0) ? W0 : (m == 1) ? W1 : (m == 2) ? W2 : (m == 3) ? W3 : W4;
    const int e = (blockIdx.x * 256 + threadIdx.x) * 4;
    float4 v = *(const float4*)(W + e);
    ushort4 o;
    o.x = f2bs(v.x); o.y = f2bs(v.y); o.z = f2bs(v.z); o.w = f2bs(v.w);
    *(ushort4*)(Wb + m * 16384 + e) = o;
}

// ---------------- Kernel PQK: Q/K/UQ/UK projections -> fragment outputs ----------------
// 1D grid 1024 = 8 XCD x 128; rt = xcd*32 + (loc>>2), m = loc&3.
// block 256 (4 waves). Grid demands only 4 blocks/CU = 4 waves/SIMD, so allow
// VGPR up to 128 (launch_bounds min-waves=4) -> deeper load pipelining.
__global__ __launch_bounds__(256, 4) void projqk_kernel(
    const float* __restrict__ EW, const float* __restrict__ ES,
    const ush* __restrict__ Wb,
    const float* __restrict__ b0, const float* __restrict__ b1,
    const float* __restrict__ b2, const float* __restrict__ b3,
    ush* __restrict__ QUf, ush* __restrict__ KUf)
{
    __shared__ ush Tls[4][2048];
    const int f = blockIdx.x;
    const int xcd = f & 7, loc = f >> 3;
    const int rt = xcd * 32 + (loc >> 2);
    const int m  = loc & 3;
    const int tid = threadIdx.x, w = tid >> 6, lane = tid & 63;
    const int l5 = lane & 31, hi = lane >> 5;
    const float* X = (m >= 2) ? ES : EW;
    const int rbase = rt * 128 + w * 32;

    const float* xr = X + (size_t)(rbase + l5) * ND + hi * 8;
    short8 af[8];
    #pragma unroll
    for (int ks = 0; ks < 8; ++ks)
        af[ks] = pack_bf8(*(const float4*)(xr + ks * 16),
                          *(const float4*)(xr + ks * 16 + 4));

    const ush* Wm = Wb + m * 16384;
    const float* Bp = (m == 0) ? b0 : (m == 1) ? b1 : (m == 2) ? b2 : b3;
    const float scl = 0.044194173824159216f;  // 1/(2*sqrt(128))

    char* Tc = (char*)Tls[w];
    ush* dstf = (m == 0 || m == 2) ? QUf : KUf;
    const int ko = (m >= 2) ? 8 : 0;
    const int p_g = rt * 4 + w;

    #pragma unroll
    for (int pass = 0; pass < 2; ++pass) {
        f32x16 acc[2];
        acc[0] = zero16(); acc[1] = zero16();
        #pragma unroll
        for (int ks = 0; ks < 8; ++ks) {
            #pragma unroll
            for (int nbl = 0; nbl < 2; ++nbl) {
                const int nb = pass * 2 + nbl;
                short8 bf_ = *(const short8*)(Wm + (nb * 32 + l5) * 128 + ks * 16 + hi * 8);
                acc[nbl] = __builtin_amdgcn_mfma_f32_32x32x16_bf16(af[ks], bf_, acc[nbl], 0, 0, 0);
            }
        }
        #pragma unroll
        for (int nbl = 0; nbl < 2; ++nbl) {
            const int nb = pass * 2 + nbl;
            float bias = Bp[nb * 32 + l5];
            #pragma unroll
            for (int r6 = 0; r6 < 16; ++r6) {
                int row = (r6 & 3) + 8 * (r6 >> 2) + 4 * hi;
                int boff = row * 128 + (((nbl * 32 + l5) * 2) ^ ((row & 7) << 4));
                *(ush*)(Tc + boff) = f2bs((acc[nbl][r6] + bias) * scl);
            }
        }
        #pragma unroll
        for (int ks8 = 0; ks8 < 4; ++ks8) {
            int boff = l5 * 128 + ((ks8 * 32 + hi * 16) ^ ((l5 & 7) << 4));
            short8 v = *(const short8*)(Tc + boff);
            int ksg = ko + pass * 4 + ks8;
            *(short8*)(dstf + ((size_t)(p_g * 16 + ksg) * 64 + lane) * 8) = v;
        }
    }
}

// ---------------- Kernel PV: V projection -> Vv fragment output ----------------
// 1D grid 256 = 8 XCD x 32; rt = (f&7)*32 + (f>>3). block 256 (4 waves).
__global__ __launch_bounds__(256, 4) void projv_kernel(
    const float* __restrict__ EW, const ush* __restrict__ Wb,
    const float* __restrict__ b4, ush* __restrict__ Vbf)
{
    __shared__ ush lds[16384];
    const int f = blockIdx.x;
    const int rt = (f & 7) * 32 + (f >> 3);
    const int tid = threadIdx.x, w = tid >> 6, lane = tid & 63;
    const int l5 = lane & 31, hi = lane >> 5;
    const int rbase = rt * 128 + w * 32;

    const float* xr = EW + (size_t)(rbase + l5) * ND + hi * 8;
    short8 af[8];
    #pragma unroll
    for (int ks = 0; ks < 8; ++ks)
        af[ks] = pack_bf8(*(const float4*)(xr + ks * 16),
                          *(const float4*)(xr + ks * 16 + 4));

    const ush* Wm = Wb + 4 * 16384;
    f32x16 acc[4];
    acc[0] = zero16(); acc[1] = zero16(); acc[2] = zero16(); acc[3] = zero16();
    #pragma unroll
    for (int ks = 0; ks < 8; ++ks) {
        #pragma unroll
        for (int nb = 0; nb < 4; ++nb) {
            short8 bf_ = *(const short8*)(Wm + (nb * 32 + l5) * 128 + ks * 16 + hi * 8);
            acc[nb] = __builtin_amdgcn_mfma_f32_32x32x16_bf16(af[ks], bf_, acc[nb], 0, 0, 0);
        }
    }

    // Vv[d][l] = value[d*4 + (l>>7)][l&127]; this block -> d in [rt*32, rt*32+32)
    char* Lc = (char*)lds;
    #pragma unroll
    for (int nb = 0; nb < 4; ++nb) {
        float bias = b4[nb * 32 + l5];
        #pragma unroll
        for (int r6 = 0; r6 < 16; ++r6) {
            int row5 = (r6 & 3) + 8 * (r6 >> 2) + 4 * hi;
            int dl = w * 8 + (row5 >> 2);
            int lcol = (row5 & 3) * 128 + nb * 32 + l5;
            int boff = dl * 1024 + ((lcol * 2) ^ ((dl & 7) << 4));
            *(ush*)(Lc + boff) = f2bs(acc[nb][r6] + bias);
        }
    }
    __syncthreads();
    #pragma unroll
    for (int it = 0; it < 8; ++it) {
        int chunk = it * 256 + tid;
        int ks = chunk >> 6, ln = chunk & 63;
        int l5b = ln & 31, hib = ln >> 5;
        int boff = l5b * 1024 + ((ks * 32 + hib * 16) ^ ((l5b & 7) << 4));
        short8 v = *(const short8*)(Lc + boff);
        *(short8*)(Vbf + ((size_t)(rt * 32 + ks) * 64 + ln) * 8) = v;
    }
}

// ---------------- Kernel A: N = exp(alpha) + partial row sums ----------------
// 1D grid 2048 = 8 XCD x 256; b = xcd*8 + (loc>>5), rt = (loc>>1)&15, ch = loc&1.
// block 256 (4 waves); rows rt*32..+31, cols ch*256..+255 (2 c-panels/wave).
__global__ __launch_bounds__(256, 4) void alpha_kernel(
    const ush* __restrict__ QUf, const ush* __restrict__ KUf,
    ush* __restrict__ Nf, float* __restrict__ dPart)
{
    __shared__ float red[4][2][16];
    __shared__ ush TlsA[4][2048];
    const int f = blockIdx.x;
    const int xcd = f & 7, loc = f >> 3;
    const int b  = xcd * 8 + (loc >> 5);
    const int rt = (loc >> 1) & 15;
    const int ch = loc & 1;
    const int tid = threadIdx.x, w = tid >> 6, lane = tid & 63;
    const int l5 = lane & 31, hi = lane >> 5;
    const ush* Qb = QUf + (size_t)b * 131072;
    const ush* Kb = KUf + (size_t)b * 131072;
    ush* Nfb = Nf + (size_t)b * 262144;

    const ush* qp = Qb + (size_t)rt * 8192 + lane * 8;
    const int cpg0 = ch * 8 + w * 2;

    f32x16 a0[2], a1[2];
    a0[0] = zero16(); a0[1] = zero16(); a1[0] = zero16(); a1[1] = zero16();
    #pragma unroll
    for (int ks = 0; ks < 16; ks += 2) {
        short8 aqa = *(const short8*)(qp + ks * 512);
        short8 aqb = *(const short8*)(qp + (ks + 1) * 512);
        #pragma unroll
        for (int cp = 0; cp < 2; ++cp) {
            const ush* kp = Kb + (size_t)((cpg0 + cp) * 16) * 512 + lane * 8;
            a0[cp] = __builtin_amdgcn_mfma_f32_32x32x16_bf16(aqa,
                         *(const short8*)(kp + ks * 512), a0[cp], 0, 0, 0);
            a1[cp] = __builtin_amdgcn_mfma_f32_32x32x16_bf16(aqb,
                         *(const short8*)(kp + (ks + 1) * 512), a1[cp], 0, 0, 0);
        }
    }

    float rs[16];
    #pragma unroll
    for (int r6 = 0; r6 < 16; ++r6) rs[r6] = 0.f;
    char* Tc = (char*)TlsA[w];
    #pragma unroll
    for (int cp = 0; cp < 2; ++cp) {
        const int cpg = cpg0 + cp;
        float e[16];
        #pragma unroll
        for (int r6 = 0; r6 < 16; ++r6) {
            e[r6] = __expf(a0[cp][r6] + a1[cp][r6]);
            rs[r6] += e[r6];
        }
        // transpose to N-frag: T[c][r], swizzle keyed by c (=l5); row-pairs as u32
        #pragma unroll
        for (int q = 0; q < 8; ++q) {
            int r6 = q * 2;
            int r = (r6 & 3) + 8 * (r6 >> 2) + 4 * hi;
            unsigned int pk = (unsigned int)f2bs(e[r6])
                            | ((unsigned int)f2bs(e[r6 + 1]) << 16);
            *(unsigned int*)(Tc + l5 * 128 + ((r * 2) ^ ((l5 & 7) << 4))) = pk;
        }
        #pragma unroll
        for (int ksl = 0; ksl < 2; ++ksl) {
            short8 v = *(const short8*)(Tc + l5 * 128 +
                           (((ksl * 16 + hi * 8) * 2) ^ ((l5 & 7) << 4)));
            int ksg = rt * 2 + ksl;
            *(short8*)(Nfb + ((size_t)(cpg * 32 + ksg) * 64 + lane) * 8) = v;
        }
    }

    // partial row sums over this block's 256 cols -> dPart[b][ch][rt*32 + l]
    #pragma unroll
    for (int mk = 1; mk <= 16; mk <<= 1)
        #pragma unroll
        for (int r6 = 0; r6 < 16; ++r6) rs[r6] += __shfl_xor(rs[r6], mk, 32);
    if (l5 == 0)
        #pragma unroll
        for (int r6 = 0; r6 < 16; ++r6) red[w][hi][r6] = rs[r6];
    __syncthreads();
    if (tid < 32) {
        int t = tid;
        int hh = (t >> 2) & 1, r6 = (t & 3) + 4 * (t >> 3);
        float s = red[0][hh][r6] + red[1][hh][r6] + red[2][hh][r6] + red[3][hh][r6];
        dPart[((size_t)b * 2 + ch) * NL + rt * 32 + t] = s;
    }
}

// ---------------- Kernel B: out = (Vv @ N) / (dPart0 + dPart1) ----------------
// 1D grid 1024 = 8 XCD x 128; b = xcd*8 + (loc>>4), ct = loc&15 (32-col tiles).
// block 256 (4 waves); wave w = d-panel, k-parity chains. Zero LDS, zero barriers.
__global__ __launch_bounds__(256, 4) void pv_kernel(
    const ush* __restrict__ Vbf, const ush* __restrict__ Nf,
    const float* __restrict__ dPart, float* __restrict__ out)
{
    const int f = blockIdx.x;
    const int xcd = f & 7, loc = f >> 3;
    const int b  = xcd * 8 + (loc >> 4);
    const int ct = loc & 15;
    const int tid = threadIdx.x, w = tid >> 6, lane = tid & 63;
    const int l5 = lane & 31, hi = lane >> 5;
    const ush* Vbb = Vbf + (size_t)b * 65536;
    const ush* Nfb = Nf + (size_t)b * 262144;
    const size_t obase = (size_t)b * (ND * NL);

    const ush* vp = Vbb + (size_t)w * 16384 + lane * 8;
    const ush* np = Nfb + (size_t)ct * 16384 + lane * 8;

    f32x16 acc0 = zero16(), acc1 = zero16();
    #pragma unroll
    for (int ks = 0; ks < 32; ks += 2) {
        acc0 = __builtin_amdgcn_mfma_f32_32x32x16_bf16(*(const short8*)(vp + ks * 512),
                   *(const short8*)(np + ks * 512), acc0, 0, 0, 0);
        acc1 = __builtin_amdgcn_mfma_f32_32x32x16_bf16(*(const short8*)(vp + (ks + 1) * 512),
                   *(const short8*)(np + (ks + 1) * 512), acc1, 0, 0, 0);
    }
    f32x16 acc = acc0 + acc1;
    const int c0 = ct * 32;
    float rd = 1.0f / (dPart[((size_t)b * 2 + 0) * NL + c0 + l5]
                     + dPart[((size_t)b * 2 + 1) * NL + c0 + l5]);
    #pragma unroll
    for (int r6 = 0; r6 < 16; ++r6) {
        int d = w * 32 + (r6 & 3) + 8 * (r6 >> 2) + 4 * hi;
        out[obase + (size_t)d * NL + c0 + l5] = acc[r6] * rd;
    }
}

// ---------------- Fallback small-ws: fused denom + result (recomputes alpha) ----------------
__global__ __launch_bounds__(256) void fused_kernel(
    const ush* __restrict__ QUf, const ush* __restrict__ KUf,
    const ush* __restrict__ Vbf, float* __restrict__ out)
{
    __shared__ ush Pt2[32 * 136];
    __shared__ float red[128];
    __shared__ float rdenS[32];
    const int f = blockIdx.x;
    const int xcd = f & 7, loc = f >> 3;
    const int b  = xcd * 8 + (loc >> 4);
    const int ct = loc & 15, c0 = ct * 32;
    const int tid = threadIdx.x, w = tid >> 6, lane = tid & 63;
    const int l5 = lane & 31, hi = lane >> 5;
    const ush* Qb  = QUf + (size_t)b * 131072;
    const ush* Kb  = KUf + (size_t)b * 131072;
    const ush* Vbb = Vbf + (size_t)b * 65536;
    const size_t obase = (size_t)b * (ND * NL);

    {
        short8 aq[16];
        const ush* qp = Qb + (size_t)ct * 8192 + lane * 8;
        #pragma unroll
        for (int ks = 0; ks < 16; ++ks) aq[ks] = *(const short8*)(qp + ks * 512);
        float rs[16];
        #pragma unroll
        for (int r = 0; r < 16; ++r) rs[r] = 0.f;
        #pragma unroll
        for (int t = 0; t < 4; ++t) {
            const ush* kp = Kb + (size_t)(w * 4 + t) * 8192 + lane * 8;
            f32x16 a0 = zero16(), a1 = zero16();
            #pragma unroll
            for (int ks = 0; ks < 16; ks += 2) {
                a0 = __builtin_amdgcn_mfma_f32_32x32x16_bf16(aq[ks],     *(const short8*)(kp + ks * 512),       a0, 0, 0, 0);
                a1 = __builtin_amdgcn_mfma_f32_32x32x16_bf16(aq[ks + 1], *(const short8*)(kp + (ks + 1) * 512), a1, 0, 0, 0);
            }
            #pragma unroll
            for (int r = 0; r < 16; ++r) rs[r] += __expf(a0[r] + a1[r]);
        }
        #pragma unroll
        for (int mk = 1; mk <= 16; mk <<= 1)
            #pragma unroll
            for (int r = 0; r < 16; ++r) rs[r] += __shfl_xor(rs[r], mk, 32);
        if (l5 == 0)
            #pragma unroll
            for (int r = 0; r < 16; ++r) red[(w * 2 + hi) * 16 + r] = rs[r];
    }
    __syncthreads();
    if (tid < 32) {
        int c = tid;
        int h2 = (c >> 2) & 1, r = (c & 3) + 4 * (c >> 3);
        float s = 0.f;
        #pragma unroll
        for (int kh = 0; kh < 4; ++kh) s += red[(kh * 2 + h2) * 16 + r];
        rdenS[c] = 1.0f / s;
    }
    __syncthreads();

    const int p2 = w;
    const float rden = rdenS[l5];
    const ush* kp2 = Kb + (size_t)ct * 8192 + lane * 8;
    f32x16 oA = zero16(), oB = zero16();

    for (int it = 0; it < 4; ++it) {
        if (it) __syncthreads();
        const ush* qp2 = Qb + (size_t)(it * 4 + p2) * 8192 + lane * 8;
        f32x16 s0 = zero16(), s1 = zero16();
        #pragma unroll
        for (int ks = 0; ks < 16; ks += 2) {
            s0 = __builtin_amdgcn_mfma_f32_32x32x16_bf16(*(const short8*)(qp2 + ks * 512),
                                                         *(const short8*)(kp2 + ks * 512),       s0, 0, 0, 0);
            s1 = __builtin_amdgcn_mfma_f32_32x32x16_bf16(*(const short8*)(qp2 + (ks + 1) * 512),
                                                         *(const short8*)(kp2 + (ks + 1) * 512), s1, 0, 0, 0);
        }
        #pragma unroll
        for (int q = 0; q < 4; ++q) {
            ushort4 pv;
            pv.x = f2bs(__expf(s0[q * 4 + 0] + s1[q * 4 + 0]) * rden);
            pv.y = f2bs(__expf(s0[q * 4 + 1] + s1[q * 4 + 1]) * rden);
            pv.z = f2bs(__expf(s0[q * 4 + 2] + s1[q * 4 + 2]) * rden);
            pv.w = f2bs(__expf(s0[q * 4 + 3] + s1[q * 4 + 3]) * rden);
            int boff = l5 * 272 + (((p2 * 32 + q * 8 + hi * 4) * 2) ^ ((l5 & 7) << 4));
            *(ushort4*)((char*)Pt2 + boff) = pv;
        }
        __syncthreads();
        #pragma unroll
        for (int j = 0; j < 8; j += 2) {
            short8 va0 = *(const short8*)(Vbb + ((size_t)(p2 * 32 + it * 8 + j) * 64 + lane) * 8);
            short8 pb0 = *(const short8*)((char*)Pt2 + l5 * 272 + (((j * 16 + hi * 8) * 2) ^ ((l5 & 7) << 4)));
            oA = __builtin_amdgcn_mfma_f32_32x32x16_bf16(va0, pb0, oA, 0, 0, 0);
            short8 va1 = *(const short8*)(Vbb + ((size_t)(p2 * 32 + it * 8 + j + 1) * 64 + lane) * 8);
            short8 pb1 = *(const short8*)((char*)Pt2 + l5 * 272 + ((((j + 1) * 16 + hi * 8) * 2) ^ ((l5 & 7) << 4)));
            oB = __builtin_amdgcn_mfma_f32_32x32x16_bf16(va1, pb1, oB, 0, 0, 0);
        }
    }
    f32x16 oacc = oA + oB;
    #pragma unroll
    for (int r = 0; r < 16; ++r) {
        int d = p2 * 32 + (r & 3) + 8 * (r >> 2) + 4 * hi;
        out[obase + (size_t)d * NL + c0 + l5] = oacc[r];
    }
}

extern "C" void kernel_launch(void* const* d_in, const int* in_sizes, int n_in,
                              void* d_out, int out_size, void* d_ws, size_t ws_size,
                              hipStream_t stream)
{
    const float* EW   = (const float*)d_in[0];
    const float* ES   = (const float*)d_in[1];
    const float* WQ_w = (const float*)d_in[2];
    const float* WQ_b = (const float*)d_in[3];
    const float* WK_w = (const float*)d_in[4];
    const float* WK_b = (const float*)d_in[5];
    const float* UQ_w = (const float*)d_in[6];
    const float* UQ_b = (const float*)d_in[7];
    const float* UK_w = (const float*)d_in[8];
    const float* UK_b = (const float*)d_in[9];
    const float* V_w  = (const float*)d_in[10];
    const float* V_b  = (const float*)d_in[11];

    // ws: QUf 16MB | KUf 16MB | Vbf 8MB | Wb 160KB | dPart 512KB @40.5MB | Nf 32MB @41MB
    if (ws_size < (size_t)41 * 1024 * 1024) return;

    char* ws = (char*)d_ws;
    ush* QUf = (ush*)ws;
    ush* KUf = (ush*)(ws + (size_t)16 * 1024 * 1024);
    ush* Vbf = (ush*)(ws + (size_t)32 * 1024 * 1024);
    ush* Wb  = (ush*)(ws + (size_t)40 * 1024 * 1024);
    float* dPart = (float*)(ws + (size_t)40 * 1024 * 1024 + 512 * 1024);
    ush* Nf  = (ush*)(ws + (size_t)41 * 1024 * 1024);
    float* outp = (float*)d_out;

    wconv_kernel<<<dim3(16, 5), 256, 0, stream>>>(WQ_w, WK_w, UQ_w, UK_w, V_w, Wb);
    projqk_kernel<<<1024, 256, 0, stream>>>(EW, ES, Wb,
                                            WQ_b, WK_b, UQ_b, UK_b, QUf, KUf);
    projv_kernel<<<256, 256, 0, stream>>>(EW, Wb, V_b, Vbf);
    if (ws_size >= (size_t)74 * 1024 * 1024) {
        alpha_kernel<<<2048, 256, 0, stream>>>(QUf, KUf, Nf, dPart);
        pv_kernel<<<1024, 256, 0, stream>>>(Vbf, Nf, dPart, outp);
    } else {
        fused_kernel<<<1024, 256, 0, stream>>>(QUf, KUf, Vbf, outp);
    }
}

// Round 17
// 80.536 us; speedup vs baseline: 1.7023x; 1.0554x over previous
//
#include <hip/hip_runtime.h>
#include <hip/hip_bf16.h>

#define NB 64
#define NL 512
#define ND 128
#define NK 256   // concat(Q,UQ) contraction dim

typedef unsigned short ush;
typedef __attribute__((ext_vector_type(8))) short short8;
typedef __attribute__((ext_vector_type(16))) float f32x16;

// Fragment layouts (bf16), one 32x32x16-MFMA operand chunk per lane:
//  QU_f/KU_f: elem off = ((p*16 + ks)*64 + lane)*8 ; holds row p*32+(lane&31),
//             k = ks*16+(lane>>5)*8 .. +7.  p GLOBAL row-panel (batch*16 + local).
//  Vb_f:      elem off = ((p*32 + ks)*64 + lane)*8 ; holds Vv row p*32+(lane&31),
//             l = ks*16+(lane>>5)*8 .. +7.  p GLOBAL (= rt).
//  N_f:       elem off = ((cp*32 + ks)*64 + lane)*8 ; holds N col cp*32+(lane&31),
//             l = ks*16+(lane>>5)*8 .. +7.  cp batch-local [0,16), ks [0,32).

__device__ __forceinline__ ush f2bs(float f) {
    union { __hip_bfloat16 h; ush u; } cv;
    cv.h = __float2bfloat16(f);
    return cv.u;
}
__device__ __forceinline__ short8 pack_bf8(float4 a, float4 b) {
    short8 r;
    r[0] = (short)f2bs(a.x); r[1] = (short)f2bs(a.y);
    r[2] = (short)f2bs(a.z); r[3] = (short)f2bs(a.w);
    r[4] = (short)f2bs(b.x); r[5] = (short)f2bs(b.y);
    r[6] = (short)f2bs(b.z); r[7] = (short)f2bs(b.w);
    return r;
}
__device__ __forceinline__ f32x16 zero16() {
    f32x16 z = {0.f,0.f,0.f,0.f,0.f,0.f,0.f,0.f,0.f,0.f,0.f,0.f,0.f,0.f,0.f,0.f};
    return z;
}

// ---------------- Kernel W: convert 5 weight matrices to bf16 ----------------
__global__ __launch_bounds__(256) void wconv_kernel(
    const float* __restrict__ W0, const float* __restrict__ W1,
    const float* __restrict__ W2, const float* __restrict__ W3,
    const float* __restrict__ W4, ush* __restrict__ Wb)
{
    const int m = blockIdx.y;
    const float* W = (m == 0) ? W0 : (m == 1) ? W1 : (m == 2) ? W2 : (m == 3) ? W3 : W4;
    const int e = (blockIdx.x * 256 + threadIdx.x) * 4;
    float4 v = *(const float4*)(W + e);
    ushort4 o;
    o.x = f2bs(v.x); o.y = f2bs(v.y); o.z = f2bs(v.z); o.w = f2bs(v.w);
    *(ushort4*)(Wb + m * 16384 + e) = o;
}

// ---------------- Kernel PQK: Q/K/UQ/UK projections -> fragment outputs ----------------
// 1D grid 1024 = 8 XCD x 128; rt = xcd*32 + (loc>>2), m = loc&3.
// block 256 (4 waves); wave w -> rows rt*128 + w*32. W direct from global (L2-hot).
// Per-pass acc[2] (32 VGPR live) -> compiler can pipeline W loads.
__global__ __launch_bounds__(256) void projqk_kernel(
    const float* __restrict__ EW, const float* __restrict__ ES,
    const ush* __restrict__ Wb,
    const float* __restrict__ b0, const float* __restrict__ b1,
    const float* __restrict__ b2, const float* __restrict__ b3,
    ush* __restrict__ QUf, ush* __restrict__ KUf)
{
    __shared__ ush Tls[4][2048];    // per-wave 4KB [32 rows][64 cols], pitch 128B
    const int f = blockIdx.x;
    const int xcd = f & 7, loc = f >> 3;          // loc 0..127
    const int rt = xcd * 32 + (loc >> 2);         // row-tile 0..255
    const int m  = loc & 3;
    const int tid = threadIdx.x, w = tid >> 6, lane = tid & 63;
    const int l5 = lane & 31, hi = lane >> 5;
    const float* X = (m >= 2) ? ES : EW;
    const int rbase = rt * 128 + w * 32;

    // pack this wave's 32 X rows into bf16 A-fragments (read once, reused both passes)
    const float* xr = X + (size_t)(rbase + l5) * ND + hi * 8;
    short8 af[8];
    #pragma unroll
    for (int ks = 0; ks < 8; ++ks)
        af[ks] = pack_bf8(*(const float4*)(xr + ks * 16),
                          *(const float4*)(xr + ks * 16 + 4));

    const ush* Wm = Wb + m * 16384;
    const float* Bp = (m == 0) ? b0 : (m == 1) ? b1 : (m == 2) ? b2 : b3;
    const float scl = 0.044194173824159216f;  // 1/(2*sqrt(128))

    char* Tc = (char*)Tls[w];
    ush* dstf = (m == 0 || m == 2) ? QUf : KUf;
    const int ko = (m >= 2) ? 8 : 0;
    const int p_g = rt * 4 + w;

    #pragma unroll
    for (int pass = 0; pass < 2; ++pass) {
        // MFMA phase for this pass's 2 col-panels only (32 acc VGPRs live)
        f32x16 acc[2];
        acc[0] = zero16(); acc[1] = zero16();
        #pragma unroll
        for (int ks = 0; ks < 8; ++ks) {
            #pragma unroll
            for (int nbl = 0; nbl < 2; ++nbl) {
                const int nb = pass * 2 + nbl;
                short8 bf_ = *(const short8*)(Wm + (nb * 32 + l5) * 128 + ks * 16 + hi * 8);
                acc[nbl] = __builtin_amdgcn_mfma_f32_32x32x16_bf16(af[ks], bf_, acc[nbl], 0, 0, 0);
            }
        }
        // transpose + fragment store for this pass
        #pragma unroll
        for (int nbl = 0; nbl < 2; ++nbl) {
            const int nb = pass * 2 + nbl;
            float bias = Bp[nb * 32 + l5];
            #pragma unroll
            for (int r6 = 0; r6 < 16; ++r6) {
                int row = (r6 & 3) + 8 * (r6 >> 2) + 4 * hi;
                int boff = row * 128 + (((nbl * 32 + l5) * 2) ^ ((row & 7) << 4));
                *(ush*)(Tc + boff) = f2bs((acc[nbl][r6] + bias) * scl);
            }
        }
        #pragma unroll
        for (int ks8 = 0; ks8 < 4; ++ks8) {
            int boff = l5 * 128 + ((ks8 * 32 + hi * 16) ^ ((l5 & 7) << 4));
            short8 v = *(const short8*)(Tc + boff);
            int ksg = ko + pass * 4 + ks8;
            *(short8*)(dstf + ((size_t)(p_g * 16 + ksg) * 64 + lane) * 8) = v;
        }
    }
}

// ---------------- Kernel PV: V projection -> Vv fragment output ----------------
// 1D grid 256 = 8 XCD x 32; rt = (f&7)*32 + (f>>3). block 256 (4 waves).
__global__ __launch_bounds__(256) void projv_kernel(
    const float* __restrict__ EW, const ush* __restrict__ Wb,
    const float* __restrict__ b4, ush* __restrict__ Vbf)
{
    __shared__ ush lds[16384];   // 32KB Vv tile [32 d][512 l], pitch 1024B
    const int f = blockIdx.x;
    const int rt = (f & 7) * 32 + (f >> 3);
    const int tid = threadIdx.x, w = tid >> 6, lane = tid & 63;
    const int l5 = lane & 31, hi = lane >> 5;
    const int rbase = rt * 128 + w * 32;

    const float* xr = EW + (size_t)(rbase + l5) * ND + hi * 8;
    short8 af[8];
    #pragma unroll
    for (int ks = 0; ks < 8; ++ks)
        af[ks] = pack_bf8(*(const float4*)(xr + ks * 16),
                          *(const float4*)(xr + ks * 16 + 4));

    const ush* Wm = Wb + 4 * 16384;
    f32x16 acc[4];
    acc[0] = zero16(); acc[1] = zero16(); acc[2] = zero16(); acc[3] = zero16();
    #pragma unroll
    for (int ks = 0; ks < 8; ++ks) {
        #pragma unroll
        for (int nb = 0; nb < 4; ++nb) {
            short8 bf_ = *(const short8*)(Wm + (nb * 32 + l5) * 128 + ks * 16 + hi * 8);
            acc[nb] = __builtin_amdgcn_mfma_f32_32x32x16_bf16(af[ks], bf_, acc[nb], 0, 0, 0);
        }
    }

    // Vv[d][l] = value[d*4 + (l>>7)][l&127]; this block -> d in [rt*32, rt*32+32)
    char* Lc = (char*)lds;
    #pragma unroll
    for (int nb = 0; nb < 4; ++nb) {
        float bias = b4[nb * 32 + l5];
        #pragma unroll
        for (int r6 = 0; r6 < 16; ++r6) {
            int row5 = (r6 & 3) + 8 * (r6 >> 2) + 4 * hi;
            int dl = w * 8 + (row5 >> 2);
            int lcol = (row5 & 3) * 128 + nb * 32 + l5;
            int boff = dl * 1024 + ((lcol * 2) ^ ((dl & 7) << 4));
            *(ush*)(Lc + boff) = f2bs(acc[nb][r6] + bias);
        }
    }
    __syncthreads();
    #pragma unroll
    for (int it = 0; it < 8; ++it) {
        int chunk = it * 256 + tid;
        int ks = chunk >> 6, ln = chunk & 63;
        int l5b = ln & 31, hib = ln >> 5;
        int boff = l5b * 1024 + ((ks * 32 + hib * 16) ^ ((l5b & 7) << 4));
        short8 v = *(const short8*)(Lc + boff);
        *(short8*)(Vbf + ((size_t)(rt * 32 + ks) * 64 + ln) * 8) = v;
    }
}

// ---------------- Kernel A: N = exp(alpha) + partial row sums ----------------
// 1D grid 2048 = 8 XCD x 256; b = xcd*8 + (loc>>5), rt = (loc>>1)&15, ch = loc&1.
// block 256 (4 waves); rows rt*32..+31, cols ch*256..+255 (2 c-panels/wave).
__global__ __launch_bounds__(256) void alpha_kernel(
    const ush* __restrict__ QUf, const ush* __restrict__ KUf,
    ush* __restrict__ Nf, float* __restrict__ dPart)
{
    __shared__ float red[4][2][16];
    __shared__ ush TlsA[4][2048];
    const int f = blockIdx.x;
    const int xcd = f & 7, loc = f >> 3;          // loc 0..255
    const int b  = xcd * 8 + (loc >> 5);
    const int rt = (loc >> 1) & 15;
    const int ch = loc & 1;
    const int tid = threadIdx.x, w = tid >> 6, lane = tid & 63;
    const int l5 = lane & 31, hi = lane >> 5;
    const ush* Qb = QUf + (size_t)b * 131072;
    const ush* Kb = KUf + (size_t)b * 131072;
    ush* Nfb = Nf + (size_t)b * 262144;

    const ush* qp = Qb + (size_t)rt * 8192 + lane * 8;
    const int cpg0 = ch * 8 + w * 2;

    f32x16 a0[2], a1[2];
    a0[0] = zero16(); a0[1] = zero16(); a1[0] = zero16(); a1[1] = zero16();
    #pragma unroll
    for (int ks = 0; ks < 16; ks += 2) {
        short8 aqa = *(const short8*)(qp + ks * 512);
        short8 aqb = *(const short8*)(qp + (ks + 1) * 512);
        #pragma unroll
        for (int cp = 0; cp < 2; ++cp) {
            const ush* kp = Kb + (size_t)((cpg0 + cp) * 16) * 512 + lane * 8;
            a0[cp] = __builtin_amdgcn_mfma_f32_32x32x16_bf16(aqa,
                         *(const short8*)(kp + ks * 512), a0[cp], 0, 0, 0);
            a1[cp] = __builtin_amdgcn_mfma_f32_32x32x16_bf16(aqb,
                         *(const short8*)(kp + (ks + 1) * 512), a1[cp], 0, 0, 0);
        }
    }

    float rs[16];
    #pragma unroll
    for (int r6 = 0; r6 < 16; ++r6) rs[r6] = 0.f;
    char* Tc = (char*)TlsA[w];
    #pragma unroll
    for (int cp = 0; cp < 2; ++cp) {
        const int cpg = cpg0 + cp;
        float e[16];
        #pragma unroll
        for (int r6 = 0; r6 < 16; ++r6) {
            e[r6] = __expf(a0[cp][r6] + a1[cp][r6]);
            rs[r6] += e[r6];
        }
        // transpose to N-frag: T[c][r], swizzle keyed by c (=l5); row-pairs as u32
        #pragma unroll
        for (int q = 0; q < 8; ++q) {
            int r6 = q * 2;
            int r = (r6 & 3) + 8 * (r6 >> 2) + 4 * hi;
            unsigned int pk = (unsigned int)f2bs(e[r6])
                            | ((unsigned int)f2bs(e[r6 + 1]) << 16);
            *(unsigned int*)(Tc + l5 * 128 + ((r * 2) ^ ((l5 & 7) << 4))) = pk;
        }
        #pragma unroll
        for (int ksl = 0; ksl < 2; ++ksl) {
            short8 v = *(const short8*)(Tc + l5 * 128 +
                           (((ksl * 16 + hi * 8) * 2) ^ ((l5 & 7) << 4)));
            int ksg = rt * 2 + ksl;
            *(short8*)(Nfb + ((size_t)(cpg * 32 + ksg) * 64 + lane) * 8) = v;
        }
    }

    // partial row sums over this block's 256 cols -> dPart[b][ch][rt*32 + l]
    #pragma unroll
    for (int mk = 1; mk <= 16; mk <<= 1)
        #pragma unroll
        for (int r6 = 0; r6 < 16; ++r6) rs[r6] += __shfl_xor(rs[r6], mk, 32);
    if (l5 == 0)
        #pragma unroll
        for (int r6 = 0; r6 < 16; ++r6) red[w][hi][r6] = rs[r6];
    __syncthreads();
    if (tid < 32) {
        int t = tid;
        int hh = (t >> 2) & 1, r6 = (t & 3) + 4 * (t >> 3);
        float s = red[0][hh][r6] + red[1][hh][r6] + red[2][hh][r6] + red[3][hh][r6];
        dPart[((size_t)b * 2 + ch) * NL + rt * 32 + t] = s;
    }
}

// ---------------- Kernel B: out = (Vv @ N) / (dPart0 + dPart1) ----------------
// 1D grid 1024 = 8 XCD x 128; b = xcd*8 + (loc>>4), ct = loc&15 (32-col tiles).
// block 256 (4 waves); wave w = d-panel, k-parity chains. Zero LDS, zero barriers.
__global__ __launch_bounds__(256) void pv_kernel(
    const ush* __restrict__ Vbf, const ush* __restrict__ Nf,
    const float* __restrict__ dPart, float* __restrict__ out)
{
    const int f = blockIdx.x;
    const int xcd = f & 7, loc = f >> 3;
    const int b  = xcd * 8 + (loc >> 4);
    const int ct = loc & 15;
    const int tid = threadIdx.x, w = tid >> 6, lane = tid & 63;
    const int l5 = lane & 31, hi = lane >> 5;
    const ush* Vbb = Vbf + (size_t)b * 65536;
    const ush* Nfb = Nf + (size_t)b * 262144;
    const size_t obase = (size_t)b * (ND * NL);

    const ush* vp = Vbb + (size_t)w * 16384 + lane * 8;
    const ush* np = Nfb + (size_t)ct * 16384 + lane * 8;

    f32x16 acc0 = zero16(), acc1 = zero16();
    #pragma unroll
    for (int ks = 0; ks < 32; ks += 2) {
        acc0 = __builtin_amdgcn_mfma_f32_32x32x16_bf16(*(const short8*)(vp + ks * 512),
                   *(const short8*)(np + ks * 512), acc0, 0, 0, 0);
        acc1 = __builtin_amdgcn_mfma_f32_32x32x16_bf16(*(const short8*)(vp + (ks + 1) * 512),
                   *(const short8*)(np + (ks + 1) * 512), acc1, 0, 0, 0);
    }
    f32x16 acc = acc0 + acc1;
    const int c0 = ct * 32;
    float rd = 1.0f / (dPart[((size_t)b * 2 + 0) * NL + c0 + l5]
                     + dPart[((size_t)b * 2 + 1) * NL + c0 + l5]);
    #pragma unroll
    for (int r6 = 0; r6 < 16; ++r6) {
        int d = w * 32 + (r6 & 3) + 8 * (r6 >> 2) + 4 * hi;
        out[obase + (size_t)d * NL + c0 + l5] = acc[r6] * rd;
    }
}

// ---------------- Fallback small-ws: fused denom + result (recomputes alpha) ----------------
__global__ __launch_bounds__(256) void fused_kernel(
    const ush* __restrict__ QUf, const ush* __restrict__ KUf,
    const ush* __restrict__ Vbf, float* __restrict__ out)
{
    __shared__ ush Pt2[32 * 136];
    __shared__ float red[128];
    __shared__ float rdenS[32];
    const int f = blockIdx.x;
    const int xcd = f & 7, loc = f >> 3;
    const int b  = xcd * 8 + (loc >> 4);
    const int ct = loc & 15, c0 = ct * 32;
    const int tid = threadIdx.x, w = tid >> 6, lane = tid & 63;
    const int l5 = lane & 31, hi = lane >> 5;
    const ush* Qb  = QUf + (size_t)b * 131072;
    const ush* Kb  = KUf + (size_t)b * 131072;
    const ush* Vbb = Vbf + (size_t)b * 65536;
    const size_t obase = (size_t)b * (ND * NL);

    {
        short8 aq[16];
        const ush* qp = Qb + (size_t)ct * 8192 + lane * 8;
        #pragma unroll
        for (int ks = 0; ks < 16; ++ks) aq[ks] = *(const short8*)(qp + ks * 512);
        float rs[16];
        #pragma unroll
        for (int r = 0; r < 16; ++r) rs[r] = 0.f;
        #pragma unroll
        for (int t = 0; t < 4; ++t) {
            const ush* kp = Kb + (size_t)(w * 4 + t) * 8192 + lane * 8;
            f32x16 a0 = zero16(), a1 = zero16();
            #pragma unroll
            for (int ks = 0; ks < 16; ks += 2) {
                a0 = __builtin_amdgcn_mfma_f32_32x32x16_bf16(aq[ks],     *(const short8*)(kp + ks * 512),       a0, 0, 0, 0);
                a1 = __builtin_amdgcn_mfma_f32_32x32x16_bf16(aq[ks + 1], *(const short8*)(kp + (ks + 1) * 512), a1, 0, 0, 0);
            }
            #pragma unroll
            for (int r = 0; r < 16; ++r) rs[r] += __expf(a0[r] + a1[r]);
        }
        #pragma unroll
        for (int mk = 1; mk <= 16; mk <<= 1)
            #pragma unroll
            for (int r = 0; r < 16; ++r) rs[r] += __shfl_xor(rs[r], mk, 32);
        if (l5 == 0)
            #pragma unroll
            for (int r = 0; r < 16; ++r) red[(w * 2 + hi) * 16 + r] = rs[r];
    }
    __syncthreads();
    if (tid < 32) {
        int c = tid;
        int h2 = (c >> 2) & 1, r = (c & 3) + 4 * (c >> 3);
        float s = 0.f;
        #pragma unroll
        for (int kh = 0; kh < 4; ++kh) s += red[(kh * 2 + h2) * 16 + r];
        rdenS[c] = 1.0f / s;
    }
    __syncthreads();

    const int p2 = w;
    const float rden = rdenS[l5];
    const ush* kp2 = Kb + (size_t)ct * 8192 + lane * 8;
    f32x16 oA = zero16(), oB = zero16();

    for (int it = 0; it < 4; ++it) {
        if (it) __syncthreads();
        const ush* qp2 = Qb + (size_t)(it * 4 + p2) * 8192 + lane * 8;
        f32x16 s0 = zero16(), s1 = zero16();
        #pragma unroll
        for (int ks = 0; ks < 16; ks += 2) {
            s0 = __builtin_amdgcn_mfma_f32_32x32x16_bf16(*(const short8*)(qp2 + ks * 512),
                                                         *(const short8*)(kp2 + ks * 512),       s0, 0, 0, 0);
            s1 = __builtin_amdgcn_mfma_f32_32x32x16_bf16(*(const short8*)(qp2 + (ks + 1) * 512),
                                                         *(const short8*)(kp2 + (ks + 1) * 512), s1, 0, 0, 0);
        }
        #pragma unroll
        for (int q = 0; q < 4; ++q) {
            ushort4 pv;
            pv.x = f2bs(__expf(s0[q * 4 + 0] + s1[q * 4 + 0]) * rden);
            pv.y = f2bs(__expf(s0[q * 4 + 1] + s1[q * 4 + 1]) * rden);
            pv.z = f2bs(__expf(s0[q * 4 + 2] + s1[q * 4 + 2]) * rden);
            pv.w = f2bs(__expf(s0[q * 4 + 3] + s1[q * 4 + 3]) * rden);
            int boff = l5 * 272 + (((p2 * 32 + q * 8 + hi * 4) * 2) ^ ((l5 & 7) << 4));
            *(ushort4*)((char*)Pt2 + boff) = pv;
        }
        __syncthreads();
        #pragma unroll
        for (int j = 0; j < 8; j += 2) {
            short8 va0 = *(const short8*)(Vbb + ((size_t)(p2 * 32 + it * 8 + j) * 64 + lane) * 8);
            short8 pb0 = *(const short8*)((char*)Pt2 + l5 * 272 + (((j * 16 + hi * 8) * 2) ^ ((l5 & 7) << 4)));
            oA = __builtin_amdgcn_mfma_f32_32x32x16_bf16(va0, pb0, oA, 0, 0, 0);
            short8 va1 = *(const short8*)(Vbb + ((size_t)(p2 * 32 + it * 8 + j + 1) * 64 + lane) * 8);
            short8 pb1 = *(const short8*)((char*)Pt2 + l5 * 272 + ((((j + 1) * 16 + hi * 8) * 2) ^ ((l5 & 7) << 4)));
            oB = __builtin_amdgcn_mfma_f32_32x32x16_bf16(va1, pb1, oB, 0, 0, 0);
        }
    }
    f32x16 oacc = oA + oB;
    #pragma unroll
    for (int r = 0; r < 16; ++r) {
        int d = p2 * 32 + (r & 3) + 8 * (r >> 2) + 4 * hi;
        out[obase + (size_t)d * NL + c0 + l5] = oacc[r];
    }
}

extern "C" void kernel_launch(void* const* d_in, const int* in_sizes, int n_in,
                              void* d_out, int out_size, void* d_ws, size_t ws_size,
                              hipStream_t stream)
{
    const float* EW   = (const float*)d_in[0];
    const float* ES   = (const float*)d_in[1];
    const float* WQ_w = (const float*)d_in[2];
    const float* WQ_b = (const float*)d_in[3];
    const float* WK_w = (const float*)d_in[4];
    const float* WK_b = (const float*)d_in[5];
    const float* UQ_w = (const float*)d_in[6];
    const float* UQ_b = (const float*)d_in[7];
    const float* UK_w = (const float*)d_in[8];
    const float* UK_b = (const float*)d_in[9];
    const float* V_w  = (const float*)d_in[10];
    const float* V_b  = (const float*)d_in[11];

    // ws: QUf 16MB | KUf 16MB | Vbf 8MB | Wb 160KB | dPart 512KB @40.5MB | Nf 32MB @41MB
    if (ws_size < (size_t)41 * 1024 * 1024) return;

    char* ws = (char*)d_ws;
    ush* QUf = (ush*)ws;
    ush* KUf = (ush*)(ws + (size_t)16 * 1024 * 1024);
    ush* Vbf = (ush*)(ws + (size_t)32 * 1024 * 1024);
    ush* Wb  = (ush*)(ws + (size_t)40 * 1024 * 1024);
    float* dPart = (float*)(ws + (size_t)40 * 1024 * 1024 + 512 * 1024);
    ush* Nf  = (ush*)(ws + (size_t)41 * 1024 * 1024);
    float* outp = (float*)d_out;

    wconv_kernel<<<dim3(16, 5), 256, 0, stream>>>(WQ_w, WK_w, UQ_w, UK_w, V_w, Wb);
    projqk_kernel<<<1024, 256, 0, stream>>>(EW, ES, Wb,
                                            WQ_b, WK_b, UQ_b, UK_b, QUf, KUf);
    projv_kernel<<<256, 256, 0, stream>>>(EW, Wb, V_b, Vbf);
    if (ws_size >= (size_t)74 * 1024 * 1024) {
        alpha_kernel<<<2048, 256, 0, stream>>>(QUf, KUf, Nf, dPart);
        pv_kernel<<<1024, 256, 0, stream>>>(Vbf, Nf, dPart, outp);
    } else {
        fused_kernel<<<1024, 256, 0, stream>>>(QUf, KUf, Vbf, outp);
    }
}

// Round 18
// 76.055 us; speedup vs baseline: 1.8026x; 1.0589x over previous
//
#include <hip/hip_runtime.h>
#include <hip/hip_bf16.h>

#define NB 64
#define NL 512
#define ND 128
#define NK 256   // concat(Q,UQ) contraction dim

typedef unsigned short ush;
typedef __attribute__((ext_vector_type(8))) short short8;
typedef __attribute__((ext_vector_type(16))) float f32x16;

// Fragment layouts, one 32x32x16-MFMA operand chunk per lane:
//  QU_f/KU_f (fp8 e4m3, scaled x16): byte off = ((p*16 + ks)*64 + lane)*8 ;
//             holds row p*32+(lane&31), k = ks*16+(lane>>5)*8 .. +7.
//             p GLOBAL row-panel (batch*16 + local). Per batch: 128KB.
//  Vb_f (bf16): elem off = ((p*32 + ks)*64 + lane)*8 ; Vv row p*32+(lane&31),
//             l = ks*16+(lane>>5)*8 .. +7.  p GLOBAL (= rt).
//  N_f (bf16): elem off = ((cp*32 + ks)*64 + lane)*8 ; N col cp*32+(lane&31),
//             l = ks*16+(lane>>5)*8 .. +7.  cp batch-local [0,16), ks [0,32).

__device__ __forceinline__ ush f2bs(float f) {
    union { __hip_bfloat16 h; ush u; } cv;
    cv.h = __float2bfloat16(f);
    return cv.u;
}
__device__ __forceinline__ float bs2f(ush u) {
    union { unsigned int i; float f; } cv;
    cv.i = ((unsigned int)u) << 16;
    return cv.f;
}
__device__ __forceinline__ short8 pack_bf8(float4 a, float4 b) {
    short8 r;
    r[0] = (short)f2bs(a.x); r[1] = (short)f2bs(a.y);
    r[2] = (short)f2bs(a.z); r[3] = (short)f2bs(a.w);
    r[4] = (short)f2bs(b.x); r[5] = (short)f2bs(b.y);
    r[6] = (short)f2bs(b.z); r[7] = (short)f2bs(b.w);
    return r;
}
__device__ __forceinline__ f32x16 zero16() {
    f32x16 z = {0.f,0.f,0.f,0.f,0.f,0.f,0.f,0.f,0.f,0.f,0.f,0.f,0.f,0.f,0.f,0.f};
    return z;
}

// ---------------- Kernel W: convert 5 weight matrices to bf16 ----------------
__global__ __launch_bounds__(256) void wconv_kernel(
    const float* __restrict__ W0, const float* __restrict__ W1,
    const float* __restrict__ W2, const float* __restrict__ W3,
    const float* __restrict__ W4, ush* __restrict__ Wb)
{
    const int m = blockIdx.y;
    const float* W = (m == 0) ? W0 : (m == 1) ? W1 : (m == 2) ? W2 : (m == 3) ? W3 : W4;
    const int e = (blockIdx.x * 256 + threadIdx.x) * 4;
    float4 v = *(const float4*)(W + e);
    ushort4 o;
    o.x = f2bs(v.x); o.y = f2bs(v.y); o.z = f2bs(v.z); o.w = f2bs(v.w);
    *(ushort4*)(Wb + m * 16384 + e) = o;
}

// ---------------- Kernel PQK: Q/K/UQ/UK projections -> fp8 fragment outputs ----------------
// 1D grid 1024 = 8 XCD x 128; rt = xcd*32 + (loc>>2), m = loc&3.
// block 256 (4 waves); wave w -> rows rt*128 + w*32. W direct from global (L2-hot).
// Values stored x16 (fp8 e4m3 normal range); alpha rescales by 1/256.
__global__ __launch_bounds__(256) void projqk_kernel(
    const float* __restrict__ EW, const float* __restrict__ ES,
    const ush* __restrict__ Wb,
    const float* __restrict__ b0, const float* __restrict__ b1,
    const float* __restrict__ b2, const float* __restrict__ b3,
    char* __restrict__ QUf, char* __restrict__ KUf)
{
    __shared__ ush Tls[4][2048];    // per-wave 4KB [32 rows][64 cols] bf16, pitch 128B
    const int f = blockIdx.x;
    const int xcd = f & 7, loc = f >> 3;          // loc 0..127
    const int rt = xcd * 32 + (loc >> 2);         // row-tile 0..255
    const int m  = loc & 3;
    const int tid = threadIdx.x, w = tid >> 6, lane = tid & 63;
    const int l5 = lane & 31, hi = lane >> 5;
    const float* X = (m >= 2) ? ES : EW;
    const int rbase = rt * 128 + w * 32;

    // pack this wave's 32 X rows into bf16 A-fragments (read once, reused both passes)
    const float* xr = X + (size_t)(rbase + l5) * ND + hi * 8;
    short8 af[8];
    #pragma unroll
    for (int ks = 0; ks < 8; ++ks)
        af[ks] = pack_bf8(*(const float4*)(xr + ks * 16),
                          *(const float4*)(xr + ks * 16 + 4));

    const ush* Wm = Wb + m * 16384;
    const float* Bp = (m == 0) ? b0 : (m == 1) ? b1 : (m == 2) ? b2 : b3;
    const float scl = 0.70710678118654752f;  // 16 / (2*sqrt(128))

    char* Tc = (char*)Tls[w];
    char* dstf = (m == 0 || m == 2) ? QUf : KUf;
    const int ko = (m >= 2) ? 8 : 0;
    const int p_g = rt * 4 + w;

    #pragma unroll
    for (int pass = 0; pass < 2; ++pass) {
        // MFMA phase for this pass's 2 col-panels (32 acc VGPRs live)
        f32x16 acc[2];
        acc[0] = zero16(); acc[1] = zero16();
        #pragma unroll
        for (int ks = 0; ks < 8; ++ks) {
            #pragma unroll
            for (int nbl = 0; nbl < 2; ++nbl) {
                const int nb = pass * 2 + nbl;
                short8 bf_ = *(const short8*)(Wm + (nb * 32 + l5) * 128 + ks * 16 + hi * 8);
                acc[nbl] = __builtin_amdgcn_mfma_f32_32x32x16_bf16(af[ks], bf_, acc[nbl], 0, 0, 0);
            }
        }
        // transpose (bf16 LDS, unchanged) + fp8 fragment store
        #pragma unroll
        for (int nbl = 0; nbl < 2; ++nbl) {
            const int nb = pass * 2 + nbl;
            float bias = Bp[nb * 32 + l5];
            #pragma unroll
            for (int r6 = 0; r6 < 16; ++r6) {
                int row = (r6 & 3) + 8 * (r6 >> 2) + 4 * hi;
                int boff = row * 128 + (((nbl * 32 + l5) * 2) ^ ((row & 7) << 4));
                *(ush*)(Tc + boff) = f2bs((acc[nbl][r6] + bias) * scl);
            }
        }
        #pragma unroll
        for (int ks8 = 0; ks8 < 4; ++ks8) {
            int boff = l5 * 128 + ((ks8 * 32 + hi * 16) ^ ((l5 & 7) << 4));
            short8 v = *(const short8*)(Tc + boff);
            float fv[8];
            #pragma unroll
            for (int e = 0; e < 8; ++e) fv[e] = bs2f((ush)v[e]);
            int dw0 = __builtin_amdgcn_cvt_pk_fp8_f32(fv[0], fv[1], 0, 0);
            dw0     = __builtin_amdgcn_cvt_pk_fp8_f32(fv[2], fv[3], dw0, 1);
            int dw1 = __builtin_amdgcn_cvt_pk_fp8_f32(fv[4], fv[5], 0, 0);
            dw1     = __builtin_amdgcn_cvt_pk_fp8_f32(fv[6], fv[7], dw1, 1);
            int ksg = ko + pass * 4 + ks8;
            int2 st; st.x = dw0; st.y = dw1;
            *(int2*)(dstf + ((size_t)(p_g * 16 + ksg) * 64 + lane) * 8) = st;
        }
    }
}

// ---------------- Kernel PV: V projection -> Vv bf16 fragment output ----------------
// 1D grid 256 = 8 XCD x 32; rt = (f&7)*32 + (f>>3). block 256 (4 waves).
__global__ __launch_bounds__(256) void projv_kernel(
    const float* __restrict__ EW, const ush* __restrict__ Wb,
    const float* __restrict__ b4, ush* __restrict__ Vbf)
{
    __shared__ ush lds[16384];   // 32KB Vv tile [32 d][512 l], pitch 1024B
    const int f = blockIdx.x;
    const int rt = (f & 7) * 32 + (f >> 3);
    const int tid = threadIdx.x, w = tid >> 6, lane = tid & 63;
    const int l5 = lane & 31, hi = lane >> 5;
    const int rbase = rt * 128 + w * 32;

    const float* xr = EW + (size_t)(rbase + l5) * ND + hi * 8;
    short8 af[8];
    #pragma unroll
    for (int ks = 0; ks < 8; ++ks)
        af[ks] = pack_bf8(*(const float4*)(xr + ks * 16),
                          *(const float4*)(xr + ks * 16 + 4));

    const ush* Wm = Wb + 4 * 16384;
    f32x16 acc[4];
    acc[0] = zero16(); acc[1] = zero16(); acc[2] = zero16(); acc[3] = zero16();
    #pragma unroll
    for (int ks = 0; ks < 8; ++ks) {
        #pragma unroll
        for (int nb = 0; nb < 4; ++nb) {
            short8 bf_ = *(const short8*)(Wm + (nb * 32 + l5) * 128 + ks * 16 + hi * 8);
            acc[nb] = __builtin_amdgcn_mfma_f32_32x32x16_bf16(af[ks], bf_, acc[nb], 0, 0, 0);
        }
    }

    // Vv[d][l] = value[d*4 + (l>>7)][l&127]; this block -> d in [rt*32, rt*32+32)
    char* Lc = (char*)lds;
    #pragma unroll
    for (int nb = 0; nb < 4; ++nb) {
        float bias = b4[nb * 32 + l5];
        #pragma unroll
        for (int r6 = 0; r6 < 16; ++r6) {
            int row5 = (r6 & 3) + 8 * (r6 >> 2) + 4 * hi;
            int dl = w * 8 + (row5 >> 2);
            int lcol = (row5 & 3) * 128 + nb * 32 + l5;
            int boff = dl * 1024 + ((lcol * 2) ^ ((dl & 7) << 4));
            *(ush*)(Lc + boff) = f2bs(acc[nb][r6] + bias);
        }
    }
    __syncthreads();
    #pragma unroll
    for (int it = 0; it < 8; ++it) {
        int chunk = it * 256 + tid;
        int ks = chunk >> 6, ln = chunk & 63;
        int l5b = ln & 31, hib = ln >> 5;
        int boff = l5b * 1024 + ((ks * 32 + hib * 16) ^ ((l5b & 7) << 4));
        short8 v = *(const short8*)(Lc + boff);
        *(short8*)(Vbf + ((size_t)(rt * 32 + ks) * 64 + ln) * 8) = v;
    }
}

// ---------------- Kernel A: N = exp(alpha) + partial row sums (fp8 operands) ----------------
// 1D grid 2048 = 8 XCD x 256; b = xcd*8 + (loc>>5), rt = (loc>>1)&15, ch = loc&1.
// block 256 (4 waves); rows rt*32..+31, cols ch*256..+255 (2 c-panels/wave).
// QU/KU stored x16 in fp8 -> alpha rescaled by 1/256 before exp.
__global__ __launch_bounds__(256) void alpha_kernel(
    const char* __restrict__ QUf, const char* __restrict__ KUf,
    ush* __restrict__ Nf, float* __restrict__ dPart)
{
    __shared__ float red[4][2][16];
    __shared__ ush TlsA[4][2048];
    const int f = blockIdx.x;
    const int xcd = f & 7, loc = f >> 3;          // loc 0..255
    const int b  = xcd * 8 + (loc >> 5);
    const int rt = (loc >> 1) & 15;
    const int ch = loc & 1;
    const int tid = threadIdx.x, w = tid >> 6, lane = tid & 63;
    const int l5 = lane & 31, hi = lane >> 5;
    const char* Qb = QUf + (size_t)b * 131072;
    const char* Kb = KUf + (size_t)b * 131072;
    ush* Nfb = Nf + (size_t)b * 262144;

    const char* qp = Qb + (size_t)rt * 8192 + lane * 8;
    const int cpg0 = ch * 8 + w * 2;
    const char* kp0 = Kb + (size_t)(cpg0 + 0) * 8192 + lane * 8;
    const char* kp1 = Kb + (size_t)(cpg0 + 1) * 8192 + lane * 8;

    f32x16 a0[2], a1[2];
    a0[0] = zero16(); a0[1] = zero16(); a1[0] = zero16(); a1[1] = zero16();
    #pragma unroll
    for (int ks = 0; ks < 16; ks += 2) {
        long aqa = *(const long*)(qp + ks * 512);
        long aqb = *(const long*)(qp + (ks + 1) * 512);
        a0[0] = __builtin_amdgcn_mfma_f32_32x32x16_fp8_fp8(aqa,
                    *(const long*)(kp0 + ks * 512), a0[0], 0, 0, 0);
        a1[0] = __builtin_amdgcn_mfma_f32_32x32x16_fp8_fp8(aqb,
                    *(const long*)(kp0 + (ks + 1) * 512), a1[0], 0, 0, 0);
        a0[1] = __builtin_amdgcn_mfma_f32_32x32x16_fp8_fp8(aqa,
                    *(const long*)(kp1 + ks * 512), a0[1], 0, 0, 0);
        a1[1] = __builtin_amdgcn_mfma_f32_32x32x16_fp8_fp8(aqb,
                    *(const long*)(kp1 + (ks + 1) * 512), a1[1], 0, 0, 0);
    }

    float rs[16];
    #pragma unroll
    for (int r6 = 0; r6 < 16; ++r6) rs[r6] = 0.f;
    char* Tc = (char*)TlsA[w];
    #pragma unroll
    for (int cp = 0; cp < 2; ++cp) {
        const int cpg = cpg0 + cp;
        float e[16];
        #pragma unroll
        for (int r6 = 0; r6 < 16; ++r6) {
            e[r6] = __expf((a0[cp][r6] + a1[cp][r6]) * 0.00390625f);  // /256
            rs[r6] += e[r6];
        }
        // transpose to N-frag (bf16): T[c][r], swizzle keyed by c (=l5); row-pairs as u32
        #pragma unroll
        for (int q = 0; q < 8; ++q) {
            int r6 = q * 2;
            int r = (r6 & 3) + 8 * (r6 >> 2) + 4 * hi;
            unsigned int pk = (unsigned int)f2bs(e[r6])
                            | ((unsigned int)f2bs(e[r6 + 1]) << 16);
            *(unsigned int*)(Tc + l5 * 128 + ((r * 2) ^ ((l5 & 7) << 4))) = pk;
        }
        #pragma unroll
        for (int ksl = 0; ksl < 2; ++ksl) {
            short8 v = *(const short8*)(Tc + l5 * 128 +
                           (((ksl * 16 + hi * 8) * 2) ^ ((l5 & 7) << 4)));
            int ksg = rt * 2 + ksl;
            *(short8*)(Nfb + ((size_t)(cpg * 32 + ksg) * 64 + lane) * 8) = v;
        }
    }

    // partial row sums over this block's 256 cols -> dPart[b][ch][rt*32 + l]
    #pragma unroll
    for (int mk = 1; mk <= 16; mk <<= 1)
        #pragma unroll
        for (int r6 = 0; r6 < 16; ++r6) rs[r6] += __shfl_xor(rs[r6], mk, 32);
    if (l5 == 0)
        #pragma unroll
        for (int r6 = 0; r6 < 16; ++r6) red[w][hi][r6] = rs[r6];
    __syncthreads();
    if (tid < 32) {
        int t = tid;
        int hh = (t >> 2) & 1, r6 = (t & 3) + 4 * (t >> 3);
        float s = red[0][hh][r6] + red[1][hh][r6] + red[2][hh][r6] + red[3][hh][r6];
        dPart[((size_t)b * 2 + ch) * NL + rt * 32 + t] = s;
    }
}

// ---------------- Kernel B: out = (Vv @ N) / (dPart0 + dPart1) ----------------
// 1D grid 1024 = 8 XCD x 128; b = xcd*8 + (loc>>4), ct = loc&15 (32-col tiles).
// block 256 (4 waves); wave w = d-panel, k-parity chains. Zero LDS, zero barriers.
__global__ __launch_bounds__(256) void pv_kernel(
    const ush* __restrict__ Vbf, const ush* __restrict__ Nf,
    const float* __restrict__ dPart, float* __restrict__ out)
{
    const int f = blockIdx.x;
    const int xcd = f & 7, loc = f >> 3;
    const int b  = xcd * 8 + (loc >> 4);
    const int ct = loc & 15;
    const int tid = threadIdx.x, w = tid >> 6, lane = tid & 63;
    const int l5 = lane & 31, hi = lane >> 5;
    const ush* Vbb = Vbf + (size_t)b * 65536;
    const ush* Nfb = Nf + (size_t)b * 262144;
    const size_t obase = (size_t)b * (ND * NL);

    const ush* vp = Vbb + (size_t)w * 16384 + lane * 8;
    const ush* np = Nfb + (size_t)ct * 16384 + lane * 8;

    f32x16 acc0 = zero16(), acc1 = zero16();
    #pragma unroll
    for (int ks = 0; ks < 32; ks += 2) {
        acc0 = __builtin_amdgcn_mfma_f32_32x32x16_bf16(*(const short8*)(vp + ks * 512),
                   *(const short8*)(np + ks * 512), acc0, 0, 0, 0);
        acc1 = __builtin_amdgcn_mfma_f32_32x32x16_bf16(*(const short8*)(vp + (ks + 1) * 512),
                   *(const short8*)(np + (ks + 1) * 512), acc1, 0, 0, 0);
    }
    f32x16 acc = acc0 + acc1;
    const int c0 = ct * 32;
    float rd = 1.0f / (dPart[((size_t)b * 2 + 0) * NL + c0 + l5]
                     + dPart[((size_t)b * 2 + 1) * NL + c0 + l5]);
    #pragma unroll
    for (int r6 = 0; r6 < 16; ++r6) {
        int d = w * 32 + (r6 & 3) + 8 * (r6 >> 2) + 4 * hi;
        out[obase + (size_t)d * NL + c0 + l5] = acc[r6] * rd;
    }
}

extern "C" void kernel_launch(void* const* d_in, const int* in_sizes, int n_in,
                              void* d_out, int out_size, void* d_ws, size_t ws_size,
                              hipStream_t stream)
{
    const float* EW   = (const float*)d_in[0];
    const float* ES   = (const float*)d_in[1];
    const float* WQ_w = (const float*)d_in[2];
    const float* WQ_b = (const float*)d_in[3];
    const float* WK_w = (const float*)d_in[4];
    const float* WK_b = (const float*)d_in[5];
    const float* UQ_w = (const float*)d_in[6];
    const float* UQ_b = (const float*)d_in[7];
    const float* UK_w = (const float*)d_in[8];
    const float* UK_b = (const float*)d_in[9];
    const float* V_w  = (const float*)d_in[10];
    const float* V_b  = (const float*)d_in[11];

    // ws: QUf fp8 8MB @0 | KUf fp8 8MB @16MB | Vbf bf16 8MB @32MB | Wb @40MB
    //     dPart @40.5MB | Nf bf16 32MB @41MB   (needs ws >= 74MB; harness gives 256MB)
    if (ws_size < (size_t)74 * 1024 * 1024) return;

    char* ws = (char*)d_ws;
    char* QUf = ws;
    char* KUf = ws + (size_t)16 * 1024 * 1024;
    ush*  Vbf = (ush*)(ws + (size_t)32 * 1024 * 1024);
    ush*  Wb  = (ush*)(ws + (size_t)40 * 1024 * 1024);
    float* dPart = (float*)(ws + (size_t)40 * 1024 * 1024 + 512 * 1024);
    ush*  Nf  = (ush*)(ws + (size_t)41 * 1024 * 1024);
    float* outp = (float*)d_out;

    wconv_kernel<<<dim3(16, 5), 256, 0, stream>>>(WQ_w, WK_w, UQ_w, UK_w, V_w, Wb);
    projqk_kernel<<<1024, 256, 0, stream>>>(EW, ES, Wb,
                                            WQ_b, WK_b, UQ_b, UK_b, QUf, KUf);
    projv_kernel<<<256, 256, 0, stream>>>(EW, Wb, V_b, Vbf);
    alpha_kernel<<<2048, 256, 0, stream>>>(QUf, KUf, Nf, dPart);
    pv_kernel<<<1024, 256, 0, stream>>>(Vbf, Nf, dPart, outp);
}